// Round 11
// baseline (7656.609 us; speedup 1.0000x reference)
//
#include <hip/hip_runtime.h>

#define KU 512
#define NB 32
#define NT 64
#define TIL 64
#define SLOTS 16
#define NBMAX 40
#define NBLK 256
#define BLKT 512

// ---- ws float offsets ----
#define N_PONG   (KU * NB * 90)
#define OFF_CEB  (N_PONG)                    // ce_sync+b_sync [512][90] f32
#define OFF_GI0  (OFF_CEB + KU * 90)         // gi0 [272] f32
#define OFF_WHTF (OFF_GI0 + 288)             // us[3][6][3][64][8] Wh       (27648 us)
#define OFF_SYF  (OFF_WHTF + 13824)          // us[6][3][64][8]    Wsync_lo (9216 us)
#define OFF_AGF  (OFF_SYF + 4608)            // us[6][3][64][8]    W_agg    (9216 us)
#define OFF_WIF  (OFF_AGF + 4608)            // us[17][3][64][8]   Wi_rnn   (26112 us)
#define OFF_WISF (OFF_WIF + 13056)           // us[17][3][64][8]   Wi_self  (26112 us)
#define OFF_WHSF (OFF_WISF + 13056)          // us[17][3][64][8]   Wh_self  (26112 us)
#define OFF_SYMF (OFF_WHSF + 13056)          // us[6][3][64][8]    Wsync_mid(9216 us)
#define OFF_WPRF (OFF_SYMF + 4608)           // us[6][6][64][8]    W_prop   (18432 us)
#define OFF_BAR  (OFF_WPRF + 9216)           // barrier state (1024 uints)

typedef short bf16x8 __attribute__((ext_vector_type(8)));
typedef float f32x4 __attribute__((ext_vector_type(4)));

__device__ __forceinline__ float sigf(float x) { return 1.0f / (1.0f + __expf(-x)); }
__device__ __forceinline__ float tanhf_(float x) {
    float e = __expf(2.0f * x);
    return 1.0f - 2.0f / (e + 1.0f);
}
__device__ __forceinline__ unsigned short f2bf(float f) {
    union { float f; unsigned u; } v; v.f = f;
    unsigned r = v.u + 0x7FFFu + ((v.u >> 16) & 1u);
    return (unsigned short)(r >> 16);
}
__device__ __forceinline__ bf16x8 cvt8(const float* p) {
    const float4 a0 = *(const float4*)p;
    const float4 a1 = *(const float4*)(p + 4);
    union { bf16x8 v; unsigned short u[8]; } fr;
    fr.u[0] = f2bf(a0.x); fr.u[1] = f2bf(a0.y); fr.u[2] = f2bf(a0.z); fr.u[3] = f2bf(a0.w);
    fr.u[4] = f2bf(a1.x); fr.u[5] = f2bf(a1.y); fr.u[6] = f2bf(a1.z); fr.u[7] = f2bf(a1.w);
    return fr.v;
}

// Two-level grid barrier: 8 sub-counters (32 arrivals each) -> master -> epoch flag.
// Poll is a relaxed agent-scope LOAD (no RMW storm); s_sleep between polls.
__device__ __forceinline__ void gridbar(unsigned* bar, unsigned ep) {
    __threadfence();
    __syncthreads();
    if (threadIdx.x == 0) {
        const int g = blockIdx.x & 7;
        const unsigned r = __hip_atomic_fetch_add(&bar[(1 + g) * 32], 1u,
                                                  __ATOMIC_ACQ_REL, __HIP_MEMORY_SCOPE_AGENT);
        if (r == 32u * ep - 1u) {
            const unsigned m = __hip_atomic_fetch_add(&bar[0], 1u,
                                                      __ATOMIC_ACQ_REL, __HIP_MEMORY_SCOPE_AGENT);
            if (m == 8u * ep - 1u)
                __hip_atomic_store(&bar[320], ep, __ATOMIC_RELEASE, __HIP_MEMORY_SCOPE_AGENT);
        }
        while (__hip_atomic_load(&bar[320], __ATOMIC_ACQUIRE, __HIP_MEMORY_SCOPE_AGENT) < ep)
            __builtin_amdgcn_s_sleep(8);
    }
    __syncthreads();
    __threadfence();
}

// ============ prep: ce_sync + gi0 + all bf16 weight fragments (once) ============
__global__ void skt_prep(const float* __restrict__ concept_emb, const float* __restrict__ W_sync,
                         const float* __restrict__ b_sync, const float* __restrict__ Wi_rnn,
                         const float* __restrict__ Wh_rnn, const float* __restrict__ Wi_self,
                         const float* __restrict__ Wh_self, const float* __restrict__ W_prop,
                         const float* __restrict__ bi_rnn, const float* __restrict__ b_agg,
                         const float* __restrict__ W_agg, float* __restrict__ ws) {
    const int blk = blockIdx.x, tid = threadIdx.x;
    if (blk < 128) {                       // ceb[512][90]
        for (int rr = 0; rr < 4; ++rr) {
            const int k = blk * 4 + rr;
            if (tid < 90) {
                float acc = b_sync[tid];
                for (int kk = 0; kk < 90; ++kk)
                    acc += concept_emb[k * 90 + kk] * W_sync[(180 + kk) * 90 + tid];
                ws[OFF_CEB + k * 90 + tid] = acc;
            }
        }
    } else if (blk < 131) {                // whtF
        const int g = blk - 128;
        unsigned short* p = (unsigned short*)(ws + OFF_WHTF);
        for (int idx = tid; idx < 9216; idx += 256) {
            const int i = idx & 7, lane = (idx >> 3) & 63;
            const int rest = idx >> 9, kk = rest % 3, nb = rest / 3;
            const int n = nb * 16 + (lane & 15);
            const int k = kk * 32 + ((lane >> 4) << 3) + i;
            p[(size_t)g * 9216 + idx] = f2bf((n < 90 && k < 90) ? Wh_rnn[k * 270 + g * 90 + n] : 0.f);
        }
    } else if (blk == 131) {               // gi0
        for (int c = tid; c < 272; c += 256) {
            float acc = 0.f;
            if (c < 270) {
                acc = bi_rnn[c];
                for (int kk = 0; kk < 90; ++kk)
                    acc += fmaxf(b_agg[kk], 0.f) * Wi_rnn[kk * 270 + c];
            }
            ws[OFF_GI0 + c] = acc;
        }
    } else if (blk == 132) {               // syF
        unsigned short* p = (unsigned short*)(ws + OFF_SYF);
        for (int idx = tid; idx < 9216; idx += 256) {
            const int i = idx & 7, lane = (idx >> 3) & 63;
            const int rest = idx >> 9, kk = rest % 3, nt = rest / 3;
            const int n = nt * 16 + (lane & 15);
            const int k = kk * 32 + ((lane >> 4) << 3) + i;
            p[idx] = f2bf((n < 90 && k < 90) ? W_sync[k * 90 + n] : 0.f);
        }
    } else if (blk == 133) {               // agF
        unsigned short* p = (unsigned short*)(ws + OFF_AGF);
        for (int idx = tid; idx < 9216; idx += 256) {
            const int i = idx & 7, lane = (idx >> 3) & 63;
            const int rest = idx >> 9, kk = rest % 3, nt = rest / 3;
            const int n = nt * 16 + (lane & 15);
            const int k = kk * 32 + ((lane >> 4) << 3) + i;
            p[idx] = f2bf((n < 90 && k < 90) ? W_agg[k * 90 + n] : 0.f);
        }
    } else if (blk < 136) {                // wiF
        unsigned short* p = (unsigned short*)(ws + OFF_WIF);
        const int i0 = (blk - 134) * 13056, i1 = i0 + 13056;
        for (int idx = i0 + tid; idx < i1; idx += 256) {
            const int i = idx & 7, lane = (idx >> 3) & 63;
            const int rest = idx >> 9, kk = rest % 3, nt = rest / 3;
            const int n = nt * 16 + (lane & 15);
            const int k = kk * 32 + ((lane >> 4) << 3) + i;
            p[idx] = f2bf((n < 270 && k < 90) ? Wi_rnn[k * 270 + n] : 0.f);
        }
    } else if (blk < 138) {                // wisF
        unsigned short* p = (unsigned short*)(ws + OFF_WISF);
        const int i0 = (blk - 136) * 13056, i1 = i0 + 13056;
        for (int idx = i0 + tid; idx < i1; idx += 256) {
            const int i = idx & 7, lane = (idx >> 3) & 63;
            const int rest = idx >> 9, kk = rest % 3, nt = rest / 3;
            const int n = nt * 16 + (lane & 15);
            const int k = kk * 32 + ((lane >> 4) << 3) + i;
            p[idx] = f2bf((n < 270 && k < 90) ? Wi_self[k * 270 + n] : 0.f);
        }
    } else if (blk < 140) {                // whsF
        unsigned short* p = (unsigned short*)(ws + OFF_WHSF);
        const int i0 = (blk - 138) * 13056, i1 = i0 + 13056;
        for (int idx = i0 + tid; idx < i1; idx += 256) {
            const int i = idx & 7, lane = (idx >> 3) & 63;
            const int rest = idx >> 9, kk = rest % 3, nt = rest / 3;
            const int n = nt * 16 + (lane & 15);
            const int k = kk * 32 + ((lane >> 4) << 3) + i;
            p[idx] = f2bf((n < 270 && k < 90) ? Wh_self[k * 270 + n] : 0.f);
        }
    } else if (blk == 140) {               // symF
        unsigned short* p = (unsigned short*)(ws + OFF_SYMF);
        for (int idx = tid; idx < 9216; idx += 256) {
            const int i = idx & 7, lane = (idx >> 3) & 63;
            const int rest = idx >> 9, kk = rest % 3, nt = rest / 3;
            const int n = nt * 16 + (lane & 15);
            const int k = kk * 32 + ((lane >> 4) << 3) + i;
            p[idx] = f2bf((n < 90 && k < 90) ? W_sync[(90 + k) * 90 + n] : 0.f);
        }
    } else {                               // wprF (K=192 padded)
        unsigned short* p = (unsigned short*)(ws + OFF_WPRF);
        for (int idx = tid; idx < 18432; idx += 256) {
            const int i = idx & 7, lane = (idx >> 3) & 63;
            const int rest = idx >> 9, kk = rest % 6, nt = rest / 6;
            const int n = nt * 16 + (lane & 15);
            const int k = kk * 32 + ((lane >> 4) << 3) + i;
            p[idx] = f2bf((n < 90 && k < 180) ? W_prop[k * 90 + n] : 0.f);
        }
    }
}

// ============ persistent step kernel: 256 blocks x 512 thr, TIL=64, hR resident ============
__global__ __launch_bounds__(BLKT, 1) void skt_run(
    const int* __restrict__ qs, const int* __restrict__ as_,
    const float* __restrict__ response_emb, const float* __restrict__ concept_emb,
    const float* __restrict__ nb_adj, const float* __restrict__ succ_adj,
    const float* __restrict__ bi_self, const float* __restrict__ bh_self,
    const float* __restrict__ bi_rnn, const float* __restrict__ bh_rnn,
    const float* __restrict__ b_agg, const float* __restrict__ b_prop,
    const float* __restrict__ W_out, const float* __restrict__ b_out,
    float* __restrict__ ws, float* __restrict__ stFinal, float* __restrict__ out,
    int t0, int t1) {
    __shared__ alignas(16) float hR[TIL * 100];
    __shared__ alignas(16) float hnb[NBMAX * 96];
    __shared__ alignas(16) float rfd[NBMAX * 92];
    __shared__ alignas(16) float giL[SLOTS * 273];
    __shared__ alignas(16) float actb[SLOTS * 96], infb[SLOTS * 96];
    __shared__ alignas(16) float giA[272], ghA[272];
    __shared__ alignas(16) float gi0L[273], biL[273], bhL[272];
    __shared__ alignas(16) float bisL[272], bhsL[272], bprL[92];
    __shared__ alignas(16) float re[96], ssv[96], ceq[92], nsv[96], xprop[192];
    __shared__ alignas(16) float nsyL[92], pvL[92], baggL[92], woutL[92];
    __shared__ float nbw[NBMAX];
    __shared__ int nblist[NBMAX];
    __shared__ float nbvL[TIL], svL[TIL];
    __shared__ int rowslotS[TIL], listS[TIL];
    __shared__ int nactS, nnbS;

    const int tid = threadIdx.x;
    const int bb = blockIdx.x >> 3;
    const int k0 = (blockIdx.x & 7) * TIL;

    const int w8 = tid >> 6, lane = tid & 63;
    const int lr = lane & 15, lh = lane >> 4;
    const int rt = w8 & 3, cg = w8 >> 2;
    const bf16x8 z8 = {0, 0, 0, 0, 0, 0, 0, 0};

    const unsigned short* whtF = (const unsigned short*)(ws + OFF_WHTF);
    const unsigned short* syF = (const unsigned short*)(ws + OFF_SYF);
    const unsigned short* agF = (const unsigned short*)(ws + OFF_AGF);
    const unsigned short* wiF = (const unsigned short*)(ws + OFF_WIF);
    const unsigned short* wisF = (const unsigned short*)(ws + OFF_WISF);
    const unsigned short* whsF = (const unsigned short*)(ws + OFF_WHSF);
    const unsigned short* symF = (const unsigned short*)(ws + OFF_SYMF);
    const unsigned short* wprF = (const unsigned short*)(ws + OFF_WPRF);
    unsigned* bar = (unsigned*)(ws + OFF_BAR);

    // ---------------- one-time setup ----------------
    for (int c = tid; c < 273; c += BLKT) {
        gi0L[c] = (c < 272) ? ws[OFF_GI0 + c] : 0.f;
        biL[c] = (c < 270) ? bi_rnn[c] : 0.f;
        if (c < 272) {
            bhL[c] = (c < 270) ? bh_rnn[c] : 0.f;
            bisL[c] = (c < 270) ? bi_self[c] : 0.f;
            bhsL[c] = (c < 270) ? bh_self[c] : 0.f;
        }
    }
    if (tid < 92) {
        baggL[tid] = (tid < 90) ? b_agg[tid] : 0.f;
        woutL[tid] = (tid < 90) ? W_out[tid] : 0.f;
        bprL[tid] = (tid < 90) ? b_prop[tid] : 0.f;
    } else if (tid < 98) {
        const int l = tid - 92;
        re[90 + l] = 0.f; ssv[90 + l] = 0.f; nsv[90 + l] = 0.f;
    } else if (tid < 110) {
        xprop[180 + (tid - 98)] = 0.f;
    } else if (tid < 302) {
        const int i = tid - 110;
        const int half = i >= SLOTS * 6;
        const int j = half ? i - SLOTS * 6 : i;
        (half ? infb : actb)[(j / 6) * 96 + 90 + (j % 6)] = 0.f;
    }
    if (t0 == 0) {
        for (int i = tid; i < TIL * 100; i += BLKT) hR[i] = 0.f;
    } else {
        const float* s0 = (t0 & 1) ? ws : stFinal;
        for (int idx = tid; idx < TIL * 50; idx += BLKT) {
            const int row = idx / 50, c2 = idx - row * 50;
            float2 v = make_float2(0.f, 0.f);
            if (c2 < 45)
                v = ((const float2*)(s0 + ((size_t)(bb * KU + k0 + row)) * 90))[c2];
            *(float2*)&hR[row * 100 + 2 * c2] = v;
        }
    }
    __syncthreads();

    // ================= TIME LOOP =================
    for (int t = t0; t < t1; ++t) {
        const float* stIn = (t & 1) ? ws : stFinal;
        float* stOut = (t & 1) ? stFinal : ws;
        const int q = qs[bb * NT + t];
        const int a = as_[bb * NT + t];
        const bool owner = (q >= k0 && q < k0 + TIL);

        // ---------- B0: scans + per-step vectors ----------
        if (tid >= 384 && tid < 448) {       // wave 6: active-row scan
            const int l = tid - 384;
            const int kg = k0 + l;
            const float nv = nb_adj[(size_t)q * KU + kg];
            const float sv = succ_adj[(size_t)q * KU + kg];
            nbvL[l] = nv; svL[l] = sv;
            const bool act = (nv != 0.f) || (sv != 0.f) || (kg == q);
            const unsigned long long mb = __ballot(act);
            const int rank = (int)__popcll(mb & ((1ull << l) - 1ull));
            rowslotS[l] = act ? rank : -1;
            if (act) listS[rank] = l;
            if (l == 0) nactS = (int)__popcll(mb);
        } else if (tid >= 448) {             // wave 7: neighbor scan of q
            const int l = tid - 448;
            int base = 0;
            for (int ch = 0; ch < 8; ++ch) {
                const int kp = ch * 64 + l;
                const float nv = nb_adj[(size_t)q * KU + kp];
                const unsigned long long mb = __ballot(nv != 0.f);
                const int idx = base + (int)__popcll(mb & ((1ull << l) - 1ull));
                if (nv != 0.f && idx < NBMAX) { nblist[idx] = kp; nbw[idx] = nv; }
                base += (int)__popcll(mb);
            }
            if (l == 0) nnbS = (base < NBMAX) ? base : NBMAX;
        }
        if (tid < 270) {
            if (tid < 90) re[tid] = response_emb[(size_t)a * 90 + tid];
            else if (tid < 180) ssv[tid - 90] = stIn[((size_t)(bb * KU + q)) * 90 + (tid - 90)];
            else ceq[tid - 180] = concept_emb[(size_t)q * 90 + (tid - 180)];
        }
        __syncthreads();   // #B0

        // ---------- B1: owner hnb gather | self-GRU MFMA | gh MFMA ----------
        if (owner) {
            const int nnb = nnbS;
            for (int i = tid; i < nnb * 48; i += BLKT) {
                const int j = i / 48, c2 = i - j * 48;
                float2 v = make_float2(0.f, 0.f);
                if (c2 < 45)
                    v = ((const float2*)(stIn + ((size_t)(bb * KU + nblist[j])) * 90))[c2];
                *(float2*)&hnb[j * 96 + 2 * c2] = v;
            }
        }
        // self-GRU matvecs via M=2 MFMA: A row0=re, row1=ssv
        for (int nt = w8; nt < 17; nt += 8) {
            bf16x8 af[3];
#pragma unroll
            for (int kk = 0; kk < 3; ++kk)
                af[kk] = (lr == 0) ? cvt8(&re[kk * 32 + lh * 8])
                       : ((lr == 1) ? cvt8(&ssv[kk * 32 + lh * 8]) : z8);
            f32x4 dwi = f32x4{0.f, 0.f, 0.f, 0.f}, dwh = f32x4{0.f, 0.f, 0.f, 0.f};
            const unsigned short* bip = wisF + (size_t)nt * 1536 + lane * 8;
            const unsigned short* bhp = whsF + (size_t)nt * 1536 + lane * 8;
#pragma unroll
            for (int kk = 0; kk < 3; ++kk) {
                dwi = __builtin_amdgcn_mfma_f32_16x16x32_bf16(af[kk], *(const bf16x8*)(bip + kk * 512), dwi, 0, 0, 0);
                dwh = __builtin_amdgcn_mfma_f32_16x16x32_bf16(af[kk], *(const bf16x8*)(bhp + kk * 512), dwh, 0, 0, 0);
            }
            if (lh == 0) {
                const int c = nt * 16 + lr;
                if (c < 270) { giA[c] = bisL[c] + dwi[0]; ghA[c] = bhsL[c] + dwh[1]; }
            }
        }
        // gh GEMM: A = own hR rows, B = whtF
        f32x4 acc[3][3];
#pragma unroll
        for (int g = 0; g < 3; ++g)
#pragma unroll
            for (int ct = 0; ct < 3; ++ct) acc[g][ct] = f32x4{0.f, 0.f, 0.f, 0.f};
        {
            bf16x8 afr[3];
            const float* ar = &hR[(rt * 16 + lr) * 100];
#pragma unroll
            for (int kk = 0; kk < 3; ++kk) afr[kk] = cvt8(ar + kk * 32 + lh * 8);
#pragma unroll
            for (int g = 0; g < 3; ++g) {
#pragma unroll
                for (int ct = 0; ct < 3; ++ct) {
                    const int nb = cg * 3 + ct;
                    const unsigned short* bp = whtF + (size_t)(g * 6 + nb) * 1536 + lane * 8;
                    acc[g][ct] = __builtin_amdgcn_mfma_f32_16x16x32_bf16(afr[0], *(const bf16x8*)(bp), acc[g][ct], 0, 0, 0);
                    acc[g][ct] = __builtin_amdgcn_mfma_f32_16x16x32_bf16(afr[1], *(const bf16x8*)(bp + 512), acc[g][ct], 0, 0, 0);
                    acc[g][ct] = __builtin_amdgcn_mfma_f32_16x16x32_bf16(afr[2], *(const bf16x8*)(bp + 1024), acc[g][ct], 0, 0, 0);
                }
            }
        }
        __syncthreads();   // #B1

        // ---------- B2: next_self gates | owner rfd MFMA ----------
        if (tid < 90) {
            const float r = sigf(giA[tid] + ghA[tid]);
            const float z = sigf(giA[90 + tid] + ghA[90 + tid]);
            const float g = tanhf_(giA[180 + tid] + r * ghA[180 + tid]);
            const float ns = (1.f - z) * g + z * ssv[tid];
            nsv[tid] = ns;
            xprop[tid] = ns - ssv[tid];
            xprop[90 + tid] = ceq[tid];
        }
        if (owner) {
            const int nnb = nnbS;
            const int pairs = ((nnb + 15) >> 4) * 6;
            for (int p = w8; p < pairs; p += 8) {
                const int mt = p / 6, nt = p - mt * 6;
                bf16x8 af[3];
                const int jrow = mt * 16 + lr;
                if (jrow < nnb) {
                    const float* rp = &hnb[jrow * 96];
#pragma unroll
                    for (int kk = 0; kk < 3; ++kk) af[kk] = cvt8(rp + kk * 32 + lh * 8);
                } else { af[0] = z8; af[1] = z8; af[2] = z8; }
                f32x4 d = f32x4{0.f, 0.f, 0.f, 0.f};
                const unsigned short* bp = syF + (size_t)nt * 1536 + lane * 8;
                d = __builtin_amdgcn_mfma_f32_16x16x32_bf16(af[0], *(const bf16x8*)(bp), d, 0, 0, 0);
                d = __builtin_amdgcn_mfma_f32_16x16x32_bf16(af[1], *(const bf16x8*)(bp + 512), d, 0, 0, 0);
                d = __builtin_amdgcn_mfma_f32_16x16x32_bf16(af[2], *(const bf16x8*)(bp + 1024), d, 0, 0, 0);
#pragma unroll
                for (int r4 = 0; r4 < 4; ++r4) {
                    const int j = mt * 16 + lh * 4 + r4;
                    const int m = nt * 16 + lr;
                    if (j < nnb && m < 90)
                        rfd[j * 92 + m] = d[r4] + ws[OFF_CEB + (size_t)nblist[j] * 90 + m];
                }
            }
        }
        __syncthreads();   // #B2

        // ---------- B3: nsync + pvec via M=1 MFMA ----------
        for (int job = w8; job < 12; job += 8) {
            const bool isP = job >= 6;
            const int nt = isP ? job - 6 : job;
            const float* src = isP ? xprop : nsv;
            const int nkf = isP ? 6 : 3;
            const unsigned short* bp = (isP ? wprF + (size_t)nt * 3072 : symF + (size_t)nt * 1536) + lane * 8;
            f32x4 d = f32x4{0.f, 0.f, 0.f, 0.f};
            for (int kk = 0; kk < nkf; ++kk) {
                const bf16x8 av = (lr == 0) ? cvt8(&src[kk * 32 + lh * 8]) : z8;
                d = __builtin_amdgcn_mfma_f32_16x16x32_bf16(av, *(const bf16x8*)(bp + kk * 512), d, 0, 0, 0);
            }
            if (lh == 0) {
                const int m = nt * 16 + lr;
                if (m < 90) {
                    if (isP) pvL[m] = fmaxf(bprL[m] + d[0], 0.f);
                    else nsyL[m] = d[0];
                }
            }
        }
        __syncthreads();   // #B3

        // ---------- C: MFMA chains + gates (multi-pass) ----------
        const int nact = nactS;
        const int npass0 = (nact + SLOTS - 1) / SLOTS;
        const int npass = (npass0 > 0) ? npass0 : 1;
        for (int pass = 0; pass < npass; ++pass) {
            const int e0p = pass * SLOTS;
            int e1p = e0p + SLOTS; if (e1p > nact) e1p = nact;
            const int na = e1p - e0p;

            // C1: act
            if (na > 0 && w8 < 6) {
                const int nt = w8;
                bf16x8 af[3];
                if (lr < na) {
                    const float* rp = &hR[listS[e0p + lr] * 100];
#pragma unroll
                    for (int kk = 0; kk < 3; ++kk) af[kk] = cvt8(rp + kk * 32 + lh * 8);
                } else { af[0] = z8; af[1] = z8; af[2] = z8; }
                f32x4 d = f32x4{0.f, 0.f, 0.f, 0.f};
                const unsigned short* bp = syF + (size_t)nt * 1536 + lane * 8;
                d = __builtin_amdgcn_mfma_f32_16x16x32_bf16(af[0], *(const bf16x8*)(bp), d, 0, 0, 0);
                d = __builtin_amdgcn_mfma_f32_16x16x32_bf16(af[1], *(const bf16x8*)(bp + 512), d, 0, 0, 0);
                d = __builtin_amdgcn_mfma_f32_16x16x32_bf16(af[2], *(const bf16x8*)(bp + 1024), d, 0, 0, 0);
                const int m = nt * 16 + lr;
                if (m < 90) {
#pragma unroll
                    for (int r4 = 0; r4 < 4; ++r4) {
                        const int slot = lh * 4 + r4;
                        if (slot >= na) continue;
                        const int r = listS[e0p + slot];
                        const float nv = nbvL[r], sv = svL[r];
                        float s = 0.f;
                        if (nv != 0.f)
                            s = nv * fmaxf(nsyL[m] + ws[OFF_CEB + (size_t)(k0 + r) * 90 + m] + d[r4], 0.f);
                        if (k0 + r == q) {
                            const int nnb = nnbS;
                            const float nsym = nsyL[m];
                            for (int j = 0; j < nnb; ++j)
                                s += nbw[j] * fmaxf(nsym + rfd[j * 92 + m], 0.f);
                        }
                        actb[slot * 96 + m] = 0.5f * s + 0.5f * sv * pvL[m];
                    }
                }
            }
            __syncthreads();

            // C2: inf
            if (na > 0 && w8 < 6) {
                const int nt = w8;
                bf16x8 af[3];
                if (lr < na) {
                    const float* rp = &actb[lr * 96];
#pragma unroll
                    for (int kk = 0; kk < 3; ++kk) af[kk] = cvt8(rp + kk * 32 + lh * 8);
                } else { af[0] = z8; af[1] = z8; af[2] = z8; }
                f32x4 d = f32x4{0.f, 0.f, 0.f, 0.f};
                const unsigned short* bp = agF + (size_t)nt * 1536 + lane * 8;
                d = __builtin_amdgcn_mfma_f32_16x16x32_bf16(af[0], *(const bf16x8*)(bp), d, 0, 0, 0);
                d = __builtin_amdgcn_mfma_f32_16x16x32_bf16(af[1], *(const bf16x8*)(bp + 512), d, 0, 0, 0);
                d = __builtin_amdgcn_mfma_f32_16x16x32_bf16(af[2], *(const bf16x8*)(bp + 1024), d, 0, 0, 0);
                const int m = nt * 16 + lr;
                if (m < 90) {
#pragma unroll
                    for (int r4 = 0; r4 < 4; ++r4) {
                        const int slot = lh * 4 + r4;
                        if (slot < na) infb[slot * 96 + m] = fmaxf(baggL[m] + d[r4], 0.f);
                    }
                }
            }
            __syncthreads();

            // C3: gi
            if (na > 0) {
                bf16x8 af[3];
                if (lr < na) {
                    const float* rp = &infb[lr * 96];
#pragma unroll
                    for (int kk = 0; kk < 3; ++kk) af[kk] = cvt8(rp + kk * 32 + lh * 8);
                } else { af[0] = z8; af[1] = z8; af[2] = z8; }
                for (int nt = w8; nt < 17; nt += 8) {
                    f32x4 d = f32x4{0.f, 0.f, 0.f, 0.f};
                    const unsigned short* bp = wiF + (size_t)nt * 1536 + lane * 8;
                    d = __builtin_amdgcn_mfma_f32_16x16x32_bf16(af[0], *(const bf16x8*)(bp), d, 0, 0, 0);
                    d = __builtin_amdgcn_mfma_f32_16x16x32_bf16(af[1], *(const bf16x8*)(bp + 512), d, 0, 0, 0);
                    d = __builtin_amdgcn_mfma_f32_16x16x32_bf16(af[2], *(const bf16x8*)(bp + 1024), d, 0, 0, 0);
                    const int c = nt * 16 + lr;
                    if (c < 270) {
#pragma unroll
                        for (int r4 = 0; r4 < 4; ++r4) {
                            const int slot = lh * 4 + r4;
                            if (slot < na) giL[slot * 273 + c] = biL[c] + d[r4];
                        }
                    }
                }
            }
            __syncthreads();

            // C4: gates (gh acc in registers); updates hR + publishes stOut
#pragma unroll
            for (int ct = 0; ct < 3; ++ct) {
                const int m = cg * 48 + ct * 16 + lr;
                if (m < 90) {
                    const float bhr = bhL[m], bhz = bhL[90 + m], bhg = bhL[180 + m];
#pragma unroll
                    for (int r4 = 0; r4 < 4; ++r4) {
                        const int row = rt * 16 + 4 * lh + r4;
                        const int sraw = rowslotS[row];
                        const bool mine = (sraw < 0) ? (pass == 0) : (sraw >= e0p && sraw < e1p);
                        if (!mine) continue;
                        const float* gs = (sraw < 0) ? gi0L : &giL[(sraw - e0p) * 273];
                        const float rg = sigf(gs[m] + acc[0][ct][r4] + bhr);
                        const float zg = sigf(gs[90 + m] + acc[1][ct][r4] + bhz);
                        const float gg = tanhf_(gs[180 + m] + rg * (acc[2][ct][r4] + bhg));
                        const float hold = hR[row * 100 + m];
                        const float hn = (1.f - zg) * gg + zg * hold;
                        hR[row * 100 + m] = hn;
                        stOut[((size_t)(bb * KU + k0 + row)) * 90 + m] = hn;
                    }
                }
            }
            __syncthreads();
        }

        // ---------- out head (8 threads/row) ----------
        {
            const int row = tid >> 3, j = tid & 7;
            const int m0 = j * 12;
            float p = 0.f;
#pragma unroll
            for (int mm = 0; mm < 12; ++mm) {
                const int m = m0 + mm;
                if (m < 90) p += hR[row * 100 + m] * woutL[m];
            }
#pragma unroll
            for (int o = 1; o < 8; o <<= 1) p += __shfl_xor(p, o);
            if (j == 0)
                out[(size_t)t * NB * KU + (size_t)bb * KU + k0 + row] = sigf(p + b_out[0]);
        }

        if (t + 1 < t1) gridbar(bar, (unsigned)(t - t0 + 1));
    }
}

extern "C" void kernel_launch(void* const* d_in, const int* in_sizes, int n_in,
                              void* d_out, int out_size, void* d_ws, size_t ws_size,
                              hipStream_t stream) {
    const int* questions = (const int*)d_in[0];
    const int* answers = (const int*)d_in[1];
    const float* response_emb = (const float*)d_in[2];
    const float* concept_emb = (const float*)d_in[3];
    const float* nb_adj = (const float*)d_in[4];
    const float* succ_adj = (const float*)d_in[5];
    const float* Wi_self = (const float*)d_in[6];
    const float* Wh_self = (const float*)d_in[7];
    const float* bi_self = (const float*)d_in[8];
    const float* bh_self = (const float*)d_in[9];
    const float* Wi_rnn = (const float*)d_in[10];
    const float* Wh_rnn = (const float*)d_in[11];
    const float* bi_rnn = (const float*)d_in[12];
    const float* bh_rnn = (const float*)d_in[13];
    const float* W_sync = (const float*)d_in[14];
    const float* b_sync = (const float*)d_in[15];
    const float* W_prop = (const float*)d_in[16];
    const float* b_prop = (const float*)d_in[17];
    const float* W_agg = (const float*)d_in[18];
    const float* b_agg = (const float*)d_in[19];
    const float* W_out = (const float*)d_in[20];
    const float* b_out = (const float*)d_in[21];

    float* out = (float*)d_out;
    float* stFinal = out + (size_t)NT * NB * KU;   // states region of d_out
    float* ws = (float*)d_ws;

    hipMemsetAsync(stFinal, 0, (size_t)NB * KU * 90 * sizeof(float), stream);
    hipMemsetAsync((void*)(ws + OFF_BAR), 0, 4096, stream);   // barrier counters
    skt_prep<<<142, 256, 0, stream>>>(concept_emb, W_sync, b_sync, Wi_rnn, Wh_rnn,
                                      Wi_self, Wh_self, W_prop, bi_rnn, b_agg, W_agg, ws);
    // Persistent: 256 blocks (1/CU by LDS), grid == CU count -> all co-resident.
    skt_run<<<NBLK, BLKT, 0, stream>>>(
        questions, answers, response_emb, concept_emb, nb_adj, succ_adj,
        bi_self, bh_self, bi_rnn, bh_rnn, b_agg, b_prop, W_out, b_out,
        ws, stFinal, out, 0, NT);
}

// Round 13
// 3781.472 us; speedup vs baseline: 2.0248x; 2.0248x over previous
//
#include <hip/hip_runtime.h>

#define KU 512
#define NB 32
#define NT 64
#define SLOTS 22
#define NBMAX 40
#define ACTMAX 64

// ---- ws float offsets (weights/fragments only; states live in d_out) ----
#define OFF_CEB  0                           // ce_sync+b_sync [512][90] f32
#define OFF_GI0  (KU * 90)                   // gi0 [272] f32
#define OFF_WHTF (OFF_GI0 + 288)             // us[3][6][3][64][8] Wh       (27648 us)
#define OFF_SYF  (OFF_WHTF + 13824)          // us[6][3][64][8]    Wsync_lo (9216 us)
#define OFF_AGF  (OFF_SYF + 4608)            // us[6][3][64][8]    W_agg    (9216 us)
#define OFF_WIF  (OFF_AGF + 4608)            // us[17][3][64][8]   Wi_rnn   (26112 us)
#define OFF_WISF (OFF_WIF + 13056)           // us[17][3][64][8]   Wi_self  (26112 us)
#define OFF_WHSF (OFF_WISF + 13056)          // us[17][3][64][8]   Wh_self  (26112 us)
#define OFF_SYMF (OFF_WHSF + 13056)          // us[6][3][64][8]    Wsync_mid(9216 us)
#define OFF_WPRF (OFF_SYMF + 4608)           // us[6][6][64][8]    W_prop   (18432 us)

typedef short bf16x8 __attribute__((ext_vector_type(8)));
typedef float f32x4 __attribute__((ext_vector_type(4)));

__device__ __forceinline__ float sigf(float x) { return 1.0f / (1.0f + __expf(-x)); }
__device__ __forceinline__ float tanhf_(float x) {
    float e = __expf(2.0f * x);
    return 1.0f - 2.0f / (e + 1.0f);
}
__device__ __forceinline__ unsigned short f2bf(float f) {
    union { float f; unsigned u; } v; v.f = f;
    unsigned r = v.u + 0x7FFFu + ((v.u >> 16) & 1u);
    return (unsigned short)(r >> 16);
}
__device__ __forceinline__ float bf2f(unsigned short u) {
    union { unsigned u; float f; } v; v.u = (unsigned)u << 16;
    return v.f;
}
__device__ __forceinline__ bf16x8 cvt8(const float* p) {
    const float4 a0 = *(const float4*)p;
    const float4 a1 = *(const float4*)(p + 4);
    union { bf16x8 v; unsigned short u[8]; } fr;
    fr.u[0] = f2bf(a0.x); fr.u[1] = f2bf(a0.y); fr.u[2] = f2bf(a0.z); fr.u[3] = f2bf(a0.w);
    fr.u[4] = f2bf(a1.x); fr.u[5] = f2bf(a1.y); fr.u[6] = f2bf(a1.z); fr.u[7] = f2bf(a1.w);
    return fr.v;
}
__device__ __forceinline__ f32x4 mm3(const bf16x8* af, const unsigned short* bp) {
    f32x4 d = f32x4{0.f, 0.f, 0.f, 0.f};
    d = __builtin_amdgcn_mfma_f32_16x16x32_bf16(af[0], *(const bf16x8*)(bp), d, 0, 0, 0);
    d = __builtin_amdgcn_mfma_f32_16x16x32_bf16(af[1], *(const bf16x8*)(bp + 512), d, 0, 0, 0);
    d = __builtin_amdgcn_mfma_f32_16x16x32_bf16(af[2], *(const bf16x8*)(bp + 1024), d, 0, 0, 0);
    return d;
}

// ============ prep: ce_sync + gi0 + all bf16 weight fragments (once) ============
__global__ void skt_prep(const float* __restrict__ concept_emb, const float* __restrict__ W_sync,
                         const float* __restrict__ b_sync, const float* __restrict__ Wi_rnn,
                         const float* __restrict__ Wh_rnn, const float* __restrict__ Wi_self,
                         const float* __restrict__ Wh_self, const float* __restrict__ W_prop,
                         const float* __restrict__ bi_rnn, const float* __restrict__ b_agg,
                         const float* __restrict__ W_agg, float* __restrict__ ws) {
    const int blk = blockIdx.x, tid = threadIdx.x;
    if (blk < 128) {                       // ceb[512][90]
        for (int rr = 0; rr < 4; ++rr) {
            const int k = blk * 4 + rr;
            if (tid < 90) {
                float acc = b_sync[tid];
                for (int kk = 0; kk < 90; ++kk)
                    acc += concept_emb[k * 90 + kk] * W_sync[(180 + kk) * 90 + tid];
                ws[OFF_CEB + k * 90 + tid] = acc;
            }
        }
    } else if (blk < 131) {                // whtF
        const int g = blk - 128;
        unsigned short* p = (unsigned short*)(ws + OFF_WHTF);
        for (int idx = tid; idx < 9216; idx += 256) {
            const int i = idx & 7, lane = (idx >> 3) & 63;
            const int rest = idx >> 9, kk = rest % 3, nb = rest / 3;
            const int n = nb * 16 + (lane & 15);
            const int k = kk * 32 + ((lane >> 4) << 3) + i;
            p[(size_t)g * 9216 + idx] = f2bf((n < 90 && k < 90) ? Wh_rnn[k * 270 + g * 90 + n] : 0.f);
        }
    } else if (blk == 131) {               // gi0
        for (int c = tid; c < 272; c += 256) {
            float acc = 0.f;
            if (c < 270) {
                acc = bi_rnn[c];
                for (int kk = 0; kk < 90; ++kk)
                    acc += fmaxf(b_agg[kk], 0.f) * Wi_rnn[kk * 270 + c];
            }
            ws[OFF_GI0 + c] = acc;
        }
    } else if (blk == 132) {               // syF
        unsigned short* p = (unsigned short*)(ws + OFF_SYF);
        for (int idx = tid; idx < 9216; idx += 256) {
            const int i = idx & 7, lane = (idx >> 3) & 63;
            const int rest = idx >> 9, kk = rest % 3, nt = rest / 3;
            const int n = nt * 16 + (lane & 15);
            const int k = kk * 32 + ((lane >> 4) << 3) + i;
            p[idx] = f2bf((n < 90 && k < 90) ? W_sync[k * 90 + n] : 0.f);
        }
    } else if (blk == 133) {               // agF
        unsigned short* p = (unsigned short*)(ws + OFF_AGF);
        for (int idx = tid; idx < 9216; idx += 256) {
            const int i = idx & 7, lane = (idx >> 3) & 63;
            const int rest = idx >> 9, kk = rest % 3, nt = rest / 3;
            const int n = nt * 16 + (lane & 15);
            const int k = kk * 32 + ((lane >> 4) << 3) + i;
            p[idx] = f2bf((n < 90 && k < 90) ? W_agg[k * 90 + n] : 0.f);
        }
    } else if (blk < 136) {                // wiF
        unsigned short* p = (unsigned short*)(ws + OFF_WIF);
        const int i0 = (blk - 134) * 13056, i1 = i0 + 13056;
        for (int idx = i0 + tid; idx < i1; idx += 256) {
            const int i = idx & 7, lane = (idx >> 3) & 63;
            const int rest = idx >> 9, kk = rest % 3, nt = rest / 3;
            const int n = nt * 16 + (lane & 15);
            const int k = kk * 32 + ((lane >> 4) << 3) + i;
            p[idx] = f2bf((n < 270 && k < 90) ? Wi_rnn[k * 270 + n] : 0.f);
        }
    } else if (blk < 138) {                // wisF
        unsigned short* p = (unsigned short*)(ws + OFF_WISF);
        const int i0 = (blk - 136) * 13056, i1 = i0 + 13056;
        for (int idx = i0 + tid; idx < i1; idx += 256) {
            const int i = idx & 7, lane = (idx >> 3) & 63;
            const int rest = idx >> 9, kk = rest % 3, nt = rest / 3;
            const int n = nt * 16 + (lane & 15);
            const int k = kk * 32 + ((lane >> 4) << 3) + i;
            p[idx] = f2bf((n < 270 && k < 90) ? Wi_self[k * 270 + n] : 0.f);
        }
    } else if (blk < 140) {                // whsF
        unsigned short* p = (unsigned short*)(ws + OFF_WHSF);
        const int i0 = (blk - 138) * 13056, i1 = i0 + 13056;
        for (int idx = i0 + tid; idx < i1; idx += 256) {
            const int i = idx & 7, lane = (idx >> 3) & 63;
            const int rest = idx >> 9, kk = rest % 3, nt = rest / 3;
            const int n = nt * 16 + (lane & 15);
            const int k = kk * 32 + ((lane >> 4) << 3) + i;
            p[idx] = f2bf((n < 270 && k < 90) ? Wh_self[k * 270 + n] : 0.f);
        }
    } else if (blk == 140) {               // symF
        unsigned short* p = (unsigned short*)(ws + OFF_SYMF);
        for (int idx = tid; idx < 9216; idx += 256) {
            const int i = idx & 7, lane = (idx >> 3) & 63;
            const int rest = idx >> 9, kk = rest % 3, nt = rest / 3;
            const int n = nt * 16 + (lane & 15);
            const int k = kk * 32 + ((lane >> 4) << 3) + i;
            p[idx] = f2bf((n < 90 && k < 90) ? W_sync[(90 + k) * 90 + n] : 0.f);
        }
    } else {                               // wprF (K=192 padded)
        unsigned short* p = (unsigned short*)(ws + OFF_WPRF);
        for (int idx = tid; idx < 18432; idx += 256) {
            const int i = idx & 7, lane = (idx >> 3) & 63;
            const int rest = idx >> 9, kk = rest % 6, nt = rest / 6;
            const int n = nt * 16 + (lane & 15);
            const int k = kk * 32 + ((lane >> 4) << 3) + i;
            p[idx] = f2bf((n < 90 && k < 180) ? W_prop[k * 90 + n] : 0.f);
        }
    }
}

// ============ one block per batch; all 64 steps in one launch; no grid sync ============
__global__ __launch_bounds__(512, 1) void skt_run(
    const int* __restrict__ qs, const int* __restrict__ as_,
    const float* __restrict__ response_emb, const float* __restrict__ concept_emb,
    const float* __restrict__ nb_adj, const float* __restrict__ succ_adj,
    const float* __restrict__ bi_self, const float* __restrict__ bh_self,
    const float* __restrict__ bi_rnn, const float* __restrict__ bh_rnn,
    const float* __restrict__ b_agg, const float* __restrict__ b_prop,
    const float* __restrict__ W_out, const float* __restrict__ b_out,
    float* __restrict__ ws, float* __restrict__ stFinal, float* __restrict__ out) {
    __shared__ alignas(16) unsigned short stBf[KU * 96];        // bf16 state mirror
    __shared__ alignas(16) float giL[SLOTS * 273];
    __shared__ alignas(16) float actb[SLOTS * 96];
    __shared__ alignas(16) float infb[SLOTS * 96];
    __shared__ alignas(16) float giA[272], ghA[272];
    __shared__ alignas(16) float gi0L[273], biL[273];
    __shared__ alignas(16) float bhL[272], bisL[272], bhsL[272];
    __shared__ alignas(16) float re[96], ssv[96], ceq[96], nsv[96], xprop[192];
    __shared__ alignas(16) float nsyL[96], pvL[96];
    __shared__ alignas(16) float bprL[96], baggL[96], woutL[96];
    __shared__ float nbw[NBMAX];
    __shared__ int nblist[NBMAX];
    __shared__ float nvW[ACTMAX], svW[ACTMAX];
    __shared__ int listS[ACTMAX];
    __shared__ short rowslotS[KU];
    __shared__ unsigned long long maskAct[8], maskNb[8];
    __shared__ int nactS, nnbS;
    __shared__ float boutS;

    const int tid = threadIdx.x;
    const int b = blockIdx.x;
    const int w8 = tid >> 6, lane = tid & 63;
    const int lr = lane & 15, lh = lane >> 4;
    const bf16x8 z8 = {0, 0, 0, 0, 0, 0, 0, 0};

    float* stF = stFinal + (size_t)b * KU * 90;   // f32 master states (in-place, L2-resident)

    const unsigned short* whtF = (const unsigned short*)(ws + OFF_WHTF);
    const unsigned short* syF = (const unsigned short*)(ws + OFF_SYF);
    const unsigned short* agF = (const unsigned short*)(ws + OFF_AGF);
    const unsigned short* wiF = (const unsigned short*)(ws + OFF_WIF);
    const unsigned short* wisF = (const unsigned short*)(ws + OFF_WISF);
    const unsigned short* whsF = (const unsigned short*)(ws + OFF_WHSF);
    const unsigned short* symF = (const unsigned short*)(ws + OFF_SYMF);
    const unsigned short* wprF = (const unsigned short*)(ws + OFF_WPRF);

    // ---------------- prologue: biases, zeros, P0(t=0) ----------------
    for (int i = tid; i < KU * 96; i += 512) stBf[i] = 0;
    for (int c = tid; c < 273; c += 512) {
        gi0L[c] = (c < 272) ? ws[OFF_GI0 + c] : 0.f;
        biL[c] = (c < 270) ? bi_rnn[c] : 0.f;
        if (c < 272) {
            bhL[c] = (c < 270) ? bh_rnn[c] : 0.f;
            bisL[c] = (c < 270) ? bi_self[c] : 0.f;
            bhsL[c] = (c < 270) ? bh_self[c] : 0.f;
        }
    }
    if (tid < 96) {
        bprL[tid] = (tid < 90) ? b_prop[tid] : 0.f;
        baggL[tid] = (tid < 90) ? b_agg[tid] : 0.f;
        woutL[tid] = (tid < 90) ? W_out[tid] : 0.f;
        re[tid] = 0.f; ssv[tid] = 0.f; ceq[tid] = 0.f; nsv[tid] = 0.f;
        nsyL[tid] = 0.f; pvL[tid] = 0.f;
    } else if (tid < 288) {
        xprop[tid - 96] = 0.f;
    }
    for (int j = tid; j < SLOTS * 6 * 2; j += 512) {   // actb/infb pad cols 90..95 = 0
        const int half = j >= SLOTS * 6;
        const int jj = half ? j - SLOTS * 6 : j;
        (half ? infb : actb)[(jj / 6) * 96 + 90 + (jj % 6)] = 0.f;
    }
    if (tid == 0) boutS = b_out[0];
    {   // P0 for t=0 (states are all zero at t=0)
        const int q0 = qs[b * NT + 0], a0 = as_[b * NT + 0];
        const float nv = nb_adj[(size_t)q0 * KU + tid];
        const float sv = succ_adj[(size_t)q0 * KU + tid];
        const bool act = (nv != 0.f) || (sv != 0.f) || (tid == q0);
        const unsigned long long mA = __ballot(act);
        const unsigned long long mN = __ballot(nv != 0.f);
        if (lane == 0) { maskAct[w8] = mA; maskNb[w8] = mN; }
        if (tid < 90) {
            re[tid] = response_emb[(size_t)a0 * 90 + tid];
            ssv[tid] = 0.f;                           // states start at zero
            ceq[tid] = concept_emb[(size_t)q0 * 90 + tid];
        }
    }
    __syncthreads();

    // ================= TIME LOOP (fully block-local) =================
    for (int t = 0; t < NT; ++t) {
        const int q = qs[b * NT + t];

        // ---------- B1: ranks/lists + self-GRU MFMA ----------
        {
            const unsigned long long mA = maskAct[w8], mN = maskNb[w8];
            int pa = 0, pn = 0;
#pragma unroll
            for (int i = 0; i < 8; ++i) {
                if (i < w8) { pa += __popcll(maskAct[i]); pn += __popcll(maskNb[i]); }
            }
            const unsigned long long below = (1ull << lane) - 1ull;
            short slot = -1;
            if ((mA >> lane) & 1ull) {
                const int r = pa + (int)__popcll(mA & below);
                if (r < ACTMAX) {
                    slot = (short)r;
                    listS[r] = tid;
                    nvW[r] = nb_adj[(size_t)q * KU + tid];
                    svW[r] = succ_adj[(size_t)q * KU + tid];
                }
            }
            rowslotS[tid] = slot;
            if ((mN >> lane) & 1ull) {
                const int r = pn + (int)__popcll(mN & below);
                if (r < NBMAX) { nblist[r] = tid; nbw[r] = nb_adj[(size_t)q * KU + tid]; }
            }
            if (tid == 0) {
                int na = 0, nn = 0;
#pragma unroll
                for (int i = 0; i < 8; ++i) { na += __popcll(maskAct[i]); nn += __popcll(maskNb[i]); }
                nactS = (na < ACTMAX) ? na : ACTMAX;
                nnbS = (nn < NBMAX) ? nn : NBMAX;
            }
        }
        {   // self-GRU matvecs: A row0=re, row1=ssv; 17 n-tiles over 8 waves
            bf16x8 af[3];
#pragma unroll
            for (int kk = 0; kk < 3; ++kk)
                af[kk] = (lr == 0) ? cvt8(&re[kk * 32 + lh * 8])
                       : ((lr == 1) ? cvt8(&ssv[kk * 32 + lh * 8]) : z8);
            for (int nt = w8; nt < 17; nt += 8) {
                const f32x4 dwi = mm3(af, wisF + (size_t)nt * 1536 + lane * 8);
                const f32x4 dwh = mm3(af, whsF + (size_t)nt * 1536 + lane * 8);
                if (lh == 0) {
                    const int c = nt * 16 + lr;
                    if (c < 270) { giA[c] = bisL[c] + dwi[0]; ghA[c] = bhsL[c] + dwh[1]; }
                }
            }
        }
        __syncthreads();   // #B1

        // ---------- B2: next_self gates -> nsv, xprop ----------
        if (tid < 90) {
            const float r = sigf(giA[tid] + ghA[tid]);
            const float z = sigf(giA[90 + tid] + ghA[90 + tid]);
            const float g = tanhf_(giA[180 + tid] + r * ghA[180 + tid]);
            const float ns = (1.f - z) * g + z * ssv[tid];
            nsv[tid] = ns;
            xprop[tid] = ns - ssv[tid];
            xprop[90 + tid] = ceq[tid];
        }
        __syncthreads();   // #B2

        // ---------- P3a: nsync + pvec + reflec (wave-local n-slices, register reduce) ----
        const int m6 = w8 * 16 + lr;         // this wave's output column (w8 < 6)
        float reflec_reg = 0.f;              // per-lane reflec for column m6
        if (w8 < 6) {
            {   // nsync (M=1)
                bf16x8 af[3];
#pragma unroll
                for (int kk = 0; kk < 3; ++kk)
                    af[kk] = (lr == 0) ? cvt8(&nsv[kk * 32 + lh * 8]) : z8;
                const f32x4 d = mm3(af, symF + (size_t)w8 * 1536 + lane * 8);
                if (lh == 0) nsyL[m6] = (m6 < 90) ? d[0] : 0.f;
            }
            {   // pvec (M=1, K=192)
                f32x4 d = f32x4{0.f, 0.f, 0.f, 0.f};
                const unsigned short* bp = wprF + (size_t)w8 * 3072 + lane * 8;
#pragma unroll
                for (int kk = 0; kk < 6; ++kk) {
                    const bf16x8 av = (lr == 0) ? cvt8(&xprop[kk * 32 + lh * 8]) : z8;
                    d = __builtin_amdgcn_mfma_f32_16x16x32_bf16(av, *(const bf16x8*)(bp + kk * 512), d, 0, 0, 0);
                }
                if (lh == 0) pvL[m6] = (m6 < 90) ? fmaxf(bprL[m6] + d[0], 0.f) : 0.f;
            }
            {   // reflec: neighbor rows @ Wsync_lo + ceb + nsym, reduced to register
                const float nsym = nsyL[m6];           // wave-local (written above by lh==0)
                const int nnb = nnbS;
                const int mtc = (nnb + 15) >> 4;
                for (int mt = 0; mt < mtc; ++mt) {
                    bf16x8 af[3];
                    const int jrow = mt * 16 + lr;
                    if (jrow < nnb) {
                        const unsigned short* rp = stBf + nblist[jrow] * 96;
#pragma unroll
                        for (int kk = 0; kk < 3; ++kk)
                            af[kk] = *(const bf16x8*)(rp + kk * 32 + lh * 8);
                    } else { af[0] = z8; af[1] = z8; af[2] = z8; }
                    const f32x4 d = mm3(af, syF + (size_t)w8 * 1536 + lane * 8);
#pragma unroll
                    for (int r4 = 0; r4 < 4; ++r4) {
                        const int j = mt * 16 + lh * 4 + r4;
                        if (j < nnb && m6 < 90)
                            reflec_reg += nbw[j] *
                                fmaxf(nsym + ws[OFF_CEB + (size_t)nblist[j] * 90 + m6] + d[r4], 0.f);
                    }
                }
                reflec_reg += __shfl_xor(reflec_reg, 16);   // reduce over j-partition (lh)
                reflec_reg += __shfl_xor(reflec_reg, 32);
            }
        }

        // ---------- pass loop over active slots ----------
        const int nact = nactS;
        const int npass = (nact + SLOTS - 1) / SLOTS;
        for (int pass = 0; pass < npass; ++pass) {
            const int e0p = pass * SLOTS;
            int e1p = e0p + SLOTS; if (e1p > nact) e1p = nact;
            const int na = e1p - e0p;

            // P3b: act
            if (w8 < 6) {
                const int stc = (na + 15) >> 4;
                for (int st = 0; st < stc; ++st) {
                    bf16x8 af[3];
                    const int s0 = st * 16 + lr;
                    if (s0 < na) {
                        const unsigned short* rp = stBf + listS[e0p + s0] * 96;
#pragma unroll
                        for (int kk = 0; kk < 3; ++kk)
                            af[kk] = *(const bf16x8*)(rp + kk * 32 + lh * 8);
                    } else { af[0] = z8; af[1] = z8; af[2] = z8; }
                    const f32x4 d = mm3(af, syF + (size_t)w8 * 1536 + lane * 8);
                    if (m6 < 90) {
#pragma unroll
                        for (int r4 = 0; r4 < 4; ++r4) {
                            const int slot = st * 16 + lh * 4 + r4;
                            if (slot >= na) continue;
                            const int r = listS[e0p + slot];
                            const float nv = nvW[e0p + slot], sv = svW[e0p + slot];
                            float s = 0.f;
                            if (nv != 0.f)
                                s = nv * fmaxf(nsyL[m6] + ws[OFF_CEB + (size_t)r * 90 + m6] + d[r4], 0.f);
                            if (r == q) s += reflec_reg;
                            actb[slot * 96 + m6] = 0.5f * s + 0.5f * sv * pvL[m6];
                        }
                    }
                }
            }
            __syncthreads();

            // C2: inf = relu(bagg + act @ W_agg)
            if (w8 < 6) {
                const int stc = (na + 15) >> 4;
                for (int st = 0; st < stc; ++st) {
                    bf16x8 af[3];
                    const int s0 = st * 16 + lr;
                    if (s0 < na) {
                        const float* rp = &actb[s0 * 96];
#pragma unroll
                        for (int kk = 0; kk < 3; ++kk) af[kk] = cvt8(rp + kk * 32 + lh * 8);
                    } else { af[0] = z8; af[1] = z8; af[2] = z8; }
                    const f32x4 d = mm3(af, agF + (size_t)w8 * 1536 + lane * 8);
                    if (m6 < 90) {
#pragma unroll
                        for (int r4 = 0; r4 < 4; ++r4) {
                            const int slot = st * 16 + lh * 4 + r4;
                            if (slot < na) infb[slot * 96 + m6] = fmaxf(baggL[m6] + d[r4], 0.f);
                        }
                    }
                }
            }
            __syncthreads();

            // C3: gi = bi + inf @ Wi_rnn
            {
                const int stc = (na + 15) >> 4;
                for (int st = 0; st < stc; ++st) {
                    bf16x8 af[3];
                    const int s0 = st * 16 + lr;
                    if (s0 < na) {
                        const float* rp = &infb[s0 * 96];
#pragma unroll
                        for (int kk = 0; kk < 3; ++kk) af[kk] = cvt8(rp + kk * 32 + lh * 8);
                    } else { af[0] = z8; af[1] = z8; af[2] = z8; }
                    for (int nt = w8; nt < 17; nt += 8) {
                        const f32x4 d = mm3(af, wiF + (size_t)nt * 1536 + lane * 8);
                        const int c = nt * 16 + lr;
                        if (c < 270) {
#pragma unroll
                            for (int r4 = 0; r4 < 4; ++r4) {
                                const int slot = st * 16 + lh * 4 + r4;
                                if (slot < na) giL[slot * 273 + c] = biL[c] + d[r4];
                            }
                        }
                    }
                }
            }
            __syncthreads();

            // C4: gh MFMA (old stBf) + gates for this pass's rows; waves own 64-row bands
            for (int rt = 0; rt < 4; ++rt) {
                const int rowbase = w8 * 64 + rt * 16;
                bool tileHas = (pass == 0);
                if (!tileHas) {
                    const short sr = (lane < 16) ? rowslotS[rowbase + lane] : (short)-1;
                    tileHas = __any(sr >= e0p && sr < e1p);
                }
                if (!tileHas) continue;
                bf16x8 af[3];
                {
                    const unsigned short* rp = stBf + (rowbase + lr) * 96;
#pragma unroll
                    for (int kk = 0; kk < 3; ++kk)
                        af[kk] = *(const bf16x8*)(rp + kk * 32 + lh * 8);
                }
                f32x4 acc[3][6];
#pragma unroll
                for (int g = 0; g < 3; ++g)
#pragma unroll
                    for (int nt = 0; nt < 6; ++nt) {
                        acc[g][nt] = mm3(af, whtF + (size_t)(g * 6 + nt) * 1536 + lane * 8);
                    }
#pragma unroll
                for (int nt = 0; nt < 6; ++nt) {
                    const int m = nt * 16 + lr;
                    if (m >= 90) continue;
                    const float bhr = bhL[m], bhz = bhL[90 + m], bhg = bhL[180 + m];
#pragma unroll
                    for (int r4 = 0; r4 < 4; ++r4) {
                        const int row = rowbase + lh * 4 + r4;
                        const short sraw = rowslotS[row];
                        const bool mine = (sraw < 0) ? (pass == 0) : (sraw >= e0p && sraw < e1p);
                        if (!mine) continue;
                        const float* gs = (sraw < 0) ? gi0L : &giL[(sraw - e0p) * 273];
                        const float rg = sigf(gs[m] + acc[0][nt][r4] + bhr);
                        const float zg = sigf(gs[90 + m] + acc[1][nt][r4] + bhz);
                        const float gg = tanhf_(gs[180 + m] + rg * (acc[2][nt][r4] + bhg));
                        const float hold = stF[(size_t)row * 90 + m];
                        const float hn = (1.f - zg) * gg + zg * hold;
                        stF[(size_t)row * 90 + m] = hn;
                        stBf[row * 96 + m] = f2bf(hn);
                    }
                }
            }
            __syncthreads();
        }

        // ---------- out(t) + P0(t+1) ----------
        {
            float p = 0.f;
            const unsigned short* rp = stBf + tid * 96;
#pragma unroll
            for (int kk = 0; kk < 12; ++kk) {
                union { bf16x8 v; unsigned short u[8]; } fr;
                fr.v = *(const bf16x8*)(rp + kk * 8);
#pragma unroll
                for (int i = 0; i < 8; ++i) p += bf2f(fr.u[i]) * woutL[kk * 8 + i];
            }
            out[(size_t)t * NB * KU + (size_t)b * KU + tid] = sigf(p + boutS);
        }
        if (t + 1 < NT) {
            const int q1 = qs[b * NT + t + 1], a1 = as_[b * NT + t + 1];
            const float nv = nb_adj[(size_t)q1 * KU + tid];
            const float sv = succ_adj[(size_t)q1 * KU + tid];
            const bool act = (nv != 0.f) || (sv != 0.f) || (tid == q1);
            const unsigned long long mA = __ballot(act);
            const unsigned long long mN = __ballot(nv != 0.f);
            if (lane == 0) { maskAct[w8] = mA; maskNb[w8] = mN; }
            if (tid < 90) {
                re[tid] = response_emb[(size_t)a1 * 90 + tid];
                ssv[tid] = stF[(size_t)q1 * 90 + tid];
                ceq[tid] = concept_emb[(size_t)q1 * 90 + tid];
            }
        }
        __syncthreads();
    }
}

extern "C" void kernel_launch(void* const* d_in, const int* in_sizes, int n_in,
                              void* d_out, int out_size, void* d_ws, size_t ws_size,
                              hipStream_t stream) {
    const int* questions = (const int*)d_in[0];
    const int* answers = (const int*)d_in[1];
    const float* response_emb = (const float*)d_in[2];
    const float* concept_emb = (const float*)d_in[3];
    const float* nb_adj = (const float*)d_in[4];
    const float* succ_adj = (const float*)d_in[5];
    const float* Wi_self = (const float*)d_in[6];
    const float* Wh_self = (const float*)d_in[7];
    const float* bi_self = (const float*)d_in[8];
    const float* bh_self = (const float*)d_in[9];
    const float* Wi_rnn = (const float*)d_in[10];
    const float* Wh_rnn = (const float*)d_in[11];
    const float* bi_rnn = (const float*)d_in[12];
    const float* bh_rnn = (const float*)d_in[13];
    const float* W_sync = (const float*)d_in[14];
    const float* b_sync = (const float*)d_in[15];
    const float* W_prop = (const float*)d_in[16];
    const float* b_prop = (const float*)d_in[17];
    const float* W_agg = (const float*)d_in[18];
    const float* b_agg = (const float*)d_in[19];
    const float* W_out = (const float*)d_in[20];
    const float* b_out = (const float*)d_in[21];

    float* out = (float*)d_out;
    float* stFinal = out + (size_t)NT * NB * KU;   // states region of d_out (in-place master)
    float* ws = (float*)d_ws;

    hipMemsetAsync(stFinal, 0, (size_t)NB * KU * 90 * sizeof(float), stream);
    skt_prep<<<142, 256, 0, stream>>>(concept_emb, W_sync, b_sync, Wi_rnn, Wh_rnn,
                                      Wi_self, Wh_self, W_prop, bi_rnn, b_agg, W_agg, ws);
    skt_run<<<NB, 512, 0, stream>>>(
        questions, answers, response_emb, concept_emb, nb_adj, succ_adj,
        bi_self, bh_self, bi_rnn, bh_rnn, b_agg, b_prop, W_out, b_out,
        ws, stFinal, out);
}

// Round 14
// 3531.007 us; speedup vs baseline: 2.1684x; 1.0709x over previous
//
#include <hip/hip_runtime.h>

#define KU 512
#define NB 32
#define NT 64
#define TIL 64
#define SLOTS 32
#define NBMAX 40

// ---- ws float offsets ----
#define N_PONG   (KU * NB * 90)
#define OFF_CEB  (N_PONG)                    // ce_sync+b_sync [512][90] f32
#define OFF_GI0  (OFF_CEB + KU * 90)         // gi0 [272] f32
#define OFF_WHTF (OFF_GI0 + 288)             // us[3][6][3][64][8] Wh       (27648 us)
#define OFF_SYF  (OFF_WHTF + 13824)          // us[6][3][64][8]    Wsync_lo (9216 us)
#define OFF_AGF  (OFF_SYF + 4608)            // us[6][3][64][8]    W_agg    (9216 us)
#define OFF_WIF  (OFF_AGF + 4608)            // us[17][3][64][8]   Wi_rnn   (26112 us)
#define OFF_WISF (OFF_WIF + 13056)           // us[17][3][64][8]   Wi_self  (26112 us)
#define OFF_WHSF (OFF_WISF + 13056)          // us[17][3][64][8]   Wh_self  (26112 us)
#define OFF_SYMF (OFF_WHSF + 13056)          // us[6][3][64][8]    Wsync_mid(9216 us)
#define OFF_WPRF (OFF_SYMF + 4608)           // us[6][6][64][8]    W_prop   (18432 us)

typedef short bf16x8 __attribute__((ext_vector_type(8)));
typedef float f32x4 __attribute__((ext_vector_type(4)));

__device__ __forceinline__ float sigf(float x) { return 1.0f / (1.0f + __expf(-x)); }
__device__ __forceinline__ float tanhf_(float x) {
    float e = __expf(2.0f * x);
    return 1.0f - 2.0f / (e + 1.0f);
}
__device__ __forceinline__ unsigned short f2bf(float f) {
    union { float f; unsigned u; } v; v.f = f;
    unsigned r = v.u + 0x7FFFu + ((v.u >> 16) & 1u);
    return (unsigned short)(r >> 16);
}
__device__ __forceinline__ bf16x8 cvt8(const float* p) {
    const float4 a0 = *(const float4*)p;
    const float4 a1 = *(const float4*)(p + 4);
    union { bf16x8 v; unsigned short u[8]; } fr;
    fr.u[0] = f2bf(a0.x); fr.u[1] = f2bf(a0.y); fr.u[2] = f2bf(a0.z); fr.u[3] = f2bf(a0.w);
    fr.u[4] = f2bf(a1.x); fr.u[5] = f2bf(a1.y); fr.u[6] = f2bf(a1.z); fr.u[7] = f2bf(a1.w);
    return fr.v;
}
__device__ __forceinline__ f32x4 mm3(const bf16x8* af, const unsigned short* bp) {
    f32x4 d = f32x4{0.f, 0.f, 0.f, 0.f};
    d = __builtin_amdgcn_mfma_f32_16x16x32_bf16(af[0], *(const bf16x8*)(bp), d, 0, 0, 0);
    d = __builtin_amdgcn_mfma_f32_16x16x32_bf16(af[1], *(const bf16x8*)(bp + 512), d, 0, 0, 0);
    d = __builtin_amdgcn_mfma_f32_16x16x32_bf16(af[2], *(const bf16x8*)(bp + 1024), d, 0, 0, 0);
    return d;
}

// ============ prep: ce_sync + gi0 + all bf16 weight fragments (once) ============
__global__ void skt_prep(const float* __restrict__ concept_emb, const float* __restrict__ W_sync,
                         const float* __restrict__ b_sync, const float* __restrict__ Wi_rnn,
                         const float* __restrict__ Wh_rnn, const float* __restrict__ Wi_self,
                         const float* __restrict__ Wh_self, const float* __restrict__ W_prop,
                         const float* __restrict__ bi_rnn, const float* __restrict__ b_agg,
                         const float* __restrict__ W_agg, float* __restrict__ ws) {
    const int blk = blockIdx.x, tid = threadIdx.x;
    if (blk < 128) {                       // ceb[512][90]
        for (int rr = 0; rr < 4; ++rr) {
            const int k = blk * 4 + rr;
            if (tid < 90) {
                float acc = b_sync[tid];
                for (int kk = 0; kk < 90; ++kk)
                    acc += concept_emb[k * 90 + kk] * W_sync[(180 + kk) * 90 + tid];
                ws[OFF_CEB + k * 90 + tid] = acc;
            }
        }
    } else if (blk < 131) {                // whtF
        const int g = blk - 128;
        unsigned short* p = (unsigned short*)(ws + OFF_WHTF);
        for (int idx = tid; idx < 9216; idx += 256) {
            const int i = idx & 7, lane = (idx >> 3) & 63;
            const int rest = idx >> 9, kk = rest % 3, nb = rest / 3;
            const int n = nb * 16 + (lane & 15);
            const int k = kk * 32 + ((lane >> 4) << 3) + i;
            p[(size_t)g * 9216 + idx] = f2bf((n < 90 && k < 90) ? Wh_rnn[k * 270 + g * 90 + n] : 0.f);
        }
    } else if (blk == 131) {               // gi0
        for (int c = tid; c < 272; c += 256) {
            float acc = 0.f;
            if (c < 270) {
                acc = bi_rnn[c];
                for (int kk = 0; kk < 90; ++kk)
                    acc += fmaxf(b_agg[kk], 0.f) * Wi_rnn[kk * 270 + c];
            }
            ws[OFF_GI0 + c] = acc;
        }
    } else if (blk == 132) {               // syF
        unsigned short* p = (unsigned short*)(ws + OFF_SYF);
        for (int idx = tid; idx < 9216; idx += 256) {
            const int i = idx & 7, lane = (idx >> 3) & 63;
            const int rest = idx >> 9, kk = rest % 3, nt = rest / 3;
            const int n = nt * 16 + (lane & 15);
            const int k = kk * 32 + ((lane >> 4) << 3) + i;
            p[idx] = f2bf((n < 90 && k < 90) ? W_sync[k * 90 + n] : 0.f);
        }
    } else if (blk == 133) {               // agF
        unsigned short* p = (unsigned short*)(ws + OFF_AGF);
        for (int idx = tid; idx < 9216; idx += 256) {
            const int i = idx & 7, lane = (idx >> 3) & 63;
            const int rest = idx >> 9, kk = rest % 3, nt = rest / 3;
            const int n = nt * 16 + (lane & 15);
            const int k = kk * 32 + ((lane >> 4) << 3) + i;
            p[idx] = f2bf((n < 90 && k < 90) ? W_agg[k * 90 + n] : 0.f);
        }
    } else if (blk < 136) {                // wiF
        unsigned short* p = (unsigned short*)(ws + OFF_WIF);
        const int i0 = (blk - 134) * 13056, i1 = i0 + 13056;
        for (int idx = i0 + tid; idx < i1; idx += 256) {
            const int i = idx & 7, lane = (idx >> 3) & 63;
            const int rest = idx >> 9, kk = rest % 3, nt = rest / 3;
            const int n = nt * 16 + (lane & 15);
            const int k = kk * 32 + ((lane >> 4) << 3) + i;
            p[idx] = f2bf((n < 270 && k < 90) ? Wi_rnn[k * 270 + n] : 0.f);
        }
    } else if (blk < 138) {                // wisF
        unsigned short* p = (unsigned short*)(ws + OFF_WISF);
        const int i0 = (blk - 136) * 13056, i1 = i0 + 13056;
        for (int idx = i0 + tid; idx < i1; idx += 256) {
            const int i = idx & 7, lane = (idx >> 3) & 63;
            const int rest = idx >> 9, kk = rest % 3, nt = rest / 3;
            const int n = nt * 16 + (lane & 15);
            const int k = kk * 32 + ((lane >> 4) << 3) + i;
            p[idx] = f2bf((n < 270 && k < 90) ? Wi_self[k * 270 + n] : 0.f);
        }
    } else if (blk < 140) {                // whsF
        unsigned short* p = (unsigned short*)(ws + OFF_WHSF);
        const int i0 = (blk - 138) * 13056, i1 = i0 + 13056;
        for (int idx = i0 + tid; idx < i1; idx += 256) {
            const int i = idx & 7, lane = (idx >> 3) & 63;
            const int rest = idx >> 9, kk = rest % 3, nt = rest / 3;
            const int n = nt * 16 + (lane & 15);
            const int k = kk * 32 + ((lane >> 4) << 3) + i;
            p[idx] = f2bf((n < 270 && k < 90) ? Wh_self[k * 270 + n] : 0.f);
        }
    } else if (blk == 140) {               // symF
        unsigned short* p = (unsigned short*)(ws + OFF_SYMF);
        for (int idx = tid; idx < 9216; idx += 256) {
            const int i = idx & 7, lane = (idx >> 3) & 63;
            const int rest = idx >> 9, kk = rest % 3, nt = rest / 3;
            const int n = nt * 16 + (lane & 15);
            const int k = kk * 32 + ((lane >> 4) << 3) + i;
            p[idx] = f2bf((n < 90 && k < 90) ? W_sync[(90 + k) * 90 + n] : 0.f);
        }
    } else {                               // wprF (K=192 padded)
        unsigned short* p = (unsigned short*)(ws + OFF_WPRF);
        for (int idx = tid; idx < 18432; idx += 256) {
            const int i = idx & 7, lane = (idx >> 3) & 63;
            const int rest = idx >> 9, kk = rest % 6, nt = rest / 6;
            const int n = nt * 16 + (lane & 15);
            const int k = kk * 32 + ((lane >> 4) << 3) + i;
            p[idx] = f2bf((n < 90 && k < 180) ? W_prop[k * 90 + n] : 0.f);
        }
    }
}

// ============ per-step kernel: 256 blocks x 512 thr, TIL=64, 5 barriers/step ============
__global__ __launch_bounds__(512, 1) void skt_step(
    const int* __restrict__ qs, const int* __restrict__ as_,
    const float* __restrict__ response_emb, const float* __restrict__ concept_emb,
    const float* __restrict__ nb_adj, const float* __restrict__ succ_adj,
    const float* __restrict__ bi_self, const float* __restrict__ bh_self,
    const float* __restrict__ bi_rnn, const float* __restrict__ bh_rnn,
    const float* __restrict__ b_agg, const float* __restrict__ b_prop,
    const float* __restrict__ W_out, const float* __restrict__ b_out,
    float* __restrict__ ws, const float* __restrict__ stIn, float* __restrict__ stOut,
    float* __restrict__ out, int t) {
    __shared__ alignas(16) float hR[TIL * 100];
    __shared__ alignas(16) float hnb[NBMAX * 96];
    __shared__ alignas(16) float rfd[NBMAX * 92];
    __shared__ alignas(16) float giL[SLOTS * 273];
    __shared__ alignas(16) float actb[SLOTS * 96], infb[SLOTS * 96];
    __shared__ alignas(16) float giA[272], ghA[272];
    __shared__ alignas(16) float gi0L[273], biL[273], bhL[272];
    __shared__ alignas(16) float re[96], ssv[96], ceq[96];
    __shared__ alignas(16) float nsvW[6][96], xpW[6][192];
    __shared__ alignas(16) float nsyL[96], pvL[96], baggL[96], woutL[96];
    __shared__ float nbw[NBMAX];
    __shared__ int nblist[NBMAX];
    __shared__ float nbvL[TIL], svL[TIL];
    __shared__ int rowslotS[TIL], listS[TIL];
    __shared__ int nactS, nnbS;

    const int tid = threadIdx.x;
    const int bb = blockIdx.x >> 3;
    const int k0 = (blockIdx.x & 7) * TIL;
    const int q = qs[bb * NT + t];
    const int a = as_[bb * NT + t];
    const bool owner = (q >= k0 && q < k0 + TIL);

    const int w8 = tid >> 6, lane = tid & 63;
    const int lr = lane & 15, lh = lane >> 4;
    const int rt = w8 & 3, cg = w8 >> 2;
    const bf16x8 z8 = {0, 0, 0, 0, 0, 0, 0, 0};

    const unsigned short* whtF = (const unsigned short*)(ws + OFF_WHTF);
    const unsigned short* syF = (const unsigned short*)(ws + OFF_SYF);
    const unsigned short* agF = (const unsigned short*)(ws + OFF_AGF);
    const unsigned short* wiF = (const unsigned short*)(ws + OFF_WIF);
    const unsigned short* wisF = (const unsigned short*)(ws + OFF_WISF);
    const unsigned short* whsF = (const unsigned short*)(ws + OFF_WHSF);
    const unsigned short* symF = (const unsigned short*)(ws + OFF_SYMF);
    const unsigned short* wprF = (const unsigned short*)(ws + OFF_WPRF);

    // ================= B0: stage =================
    if (tid < 384) {                     // hR 64 x 50 float2 (cols 90..99 zero)
        for (int idx = tid; idx < TIL * 50; idx += 384) {
            const int row = idx / 50, c2 = idx - row * 50;
            float2 v = make_float2(0.f, 0.f);
            if (c2 < 45)
                v = ((const float2*)(stIn + ((size_t)(bb * KU + k0 + row)) * 90))[c2];
            *(float2*)&hR[row * 100 + 2 * c2] = v;
        }
    } else if (tid < 448) {              // wave 6: active-row scan
        const int l = tid - 384;
        const int kg = k0 + l;
        const float nv = nb_adj[(size_t)q * KU + kg];
        const float sv = succ_adj[(size_t)q * KU + kg];
        nbvL[l] = nv; svL[l] = sv;
        const bool act = (nv != 0.f) || (sv != 0.f) || (kg == q);
        const unsigned long long mb = __ballot(act);
        const int rank = (int)__popcll(mb & ((1ull << l) - 1ull));
        rowslotS[l] = act ? rank : -1;
        if (act) listS[rank] = l;
        if (l == 0) nactS = (int)__popcll(mb);
    } else {                             // wave 7: neighbor scan of q
        const int l = tid - 448;
        int base = 0;
        for (int ch = 0; ch < 8; ++ch) {
            const int kp = ch * 64 + l;
            const float nv = nb_adj[(size_t)q * KU + kp];
            const unsigned long long mb = __ballot(nv != 0.f);
            const int idx = base + (int)__popcll(mb & ((1ull << l) - 1ull));
            if (nv != 0.f && idx < NBMAX) { nblist[idx] = kp; nbw[idx] = nv; }
            base += (int)__popcll(mb);
        }
        if (l == 0) nnbS = (base < NBMAX) ? base : NBMAX;
    }
    for (int j = tid; j < 270; j += 512) {
        if (j < 90) re[j] = response_emb[(size_t)a * 90 + j];
        else if (j < 180) ssv[j - 90] = stIn[((size_t)(bb * KU + q)) * 90 + (j - 90)];
        else ceq[j - 180] = concept_emb[(size_t)q * 90 + (j - 180)];
    }
    for (int c = tid; c < 273; c += 512) {
        gi0L[c] = (c < 272) ? ws[OFF_GI0 + c] : 0.f;
        biL[c] = (c < 270) ? bi_rnn[c] : 0.f;
        if (c < 272) bhL[c] = (c < 270) ? bh_rnn[c] : 0.f;
    }
    if (tid < 92) {
        baggL[tid] = (tid < 90) ? b_agg[tid] : 0.f;
        woutL[tid] = (tid < 90) ? W_out[tid] : 0.f;
        if (tid >= 90) { re[tid] = 0.f; ssv[tid] = 0.f; ceq[tid] = 0.f; }
    } else if (tid < 96) { re[tid] = 0.f; ssv[tid] = 0.f; ceq[tid] = 0.f; }
    else if (tid < 132) { nsvW[(tid - 96) / 6][90 + (tid - 96) % 6] = 0.f; }
    else if (tid < 204) { xpW[(tid - 132) / 12][180 + (tid - 132) % 12] = 0.f; }
    else if (tid < 204 + SLOTS * 6) {
        const int j = tid - 204;
        actb[(j / 6) * 96 + 90 + (j % 6)] = 0.f;
    }
    for (int j = tid; j < SLOTS * 6; j += 512)
        infb[(j / 6) * 96 + 90 + (j % 6)] = 0.f;
    __syncthreads();   // ---- barrier 1 ----

    // ================= B1: self-GRU MFMA | gh GEMM | owner hnb gather =================
    if (owner) {
        const int nnb = nnbS;
        for (int i = tid; i < nnb * 48; i += 512) {
            const int j = i / 48, c2 = i - j * 48;
            float2 v = make_float2(0.f, 0.f);
            if (c2 < 45)
                v = ((const float2*)(stIn + ((size_t)(bb * KU + nblist[j])) * 90))[c2];
            *(float2*)&hnb[j * 96 + 2 * c2] = v;
        }
    }
    {   // self-GRU matvecs via M=2 MFMA: A row0=re, row1=ssv
        bf16x8 af[3];
#pragma unroll
        for (int kk = 0; kk < 3; ++kk)
            af[kk] = (lr == 0) ? cvt8(&re[kk * 32 + lh * 8])
                   : ((lr == 1) ? cvt8(&ssv[kk * 32 + lh * 8]) : z8);
        for (int nt = w8; nt < 17; nt += 8) {
            const f32x4 dwi = mm3(af, wisF + (size_t)nt * 1536 + lane * 8);
            const f32x4 dwh = mm3(af, whsF + (size_t)nt * 1536 + lane * 8);
            if (lh == 0) {
                const int c = nt * 16 + lr;
                if (c < 270) { giA[c] = bi_self[c] + dwi[0]; ghA[c] = bh_self[c] + dwh[1]; }
            }
        }
    }
    // gh GEMM: A = own hR rows, B = whtF
    f32x4 acc[3][3];
#pragma unroll
    for (int g = 0; g < 3; ++g)
#pragma unroll
        for (int ct = 0; ct < 3; ++ct) acc[g][ct] = f32x4{0.f, 0.f, 0.f, 0.f};
    {
        bf16x8 afr[3];
        const float* ar = &hR[(rt * 16 + lr) * 100];
#pragma unroll
        for (int kk = 0; kk < 3; ++kk) afr[kk] = cvt8(ar + kk * 32 + lh * 8);
#pragma unroll
        for (int g = 0; g < 3; ++g) {
#pragma unroll
            for (int ct = 0; ct < 3; ++ct) {
                const int nb = cg * 3 + ct;
                const unsigned short* bp = whtF + (size_t)(g * 6 + nb) * 1536 + lane * 8;
                acc[g][ct] = __builtin_amdgcn_mfma_f32_16x16x32_bf16(afr[0], *(const bf16x8*)(bp), acc[g][ct], 0, 0, 0);
                acc[g][ct] = __builtin_amdgcn_mfma_f32_16x16x32_bf16(afr[1], *(const bf16x8*)(bp + 512), acc[g][ct], 0, 0, 0);
                acc[g][ct] = __builtin_amdgcn_mfma_f32_16x16x32_bf16(afr[2], *(const bf16x8*)(bp + 1024), acc[g][ct], 0, 0, 0);
            }
        }
    }
    __syncthreads();   // ---- barrier 2 ----

    // ================= B2': nsv/xprop per-wave -> nsync+pvec (w<6) | rfd (w6-7, owner) ====
    const int m6 = w8 * 16 + lr;
    if (w8 < 6) {
        {   // wave-local nsv / xprop (redundant per wave; identical f32 math)
            const int l1 = lane, l2 = lane + 64;
            if (l1 < 90) {
                const float r = sigf(giA[l1] + ghA[l1]);
                const float z = sigf(giA[90 + l1] + ghA[90 + l1]);
                const float g = tanhf_(giA[180 + l1] + r * ghA[180 + l1]);
                const float ns = (1.f - z) * g + z * ssv[l1];
                nsvW[w8][l1] = ns;
                xpW[w8][l1] = ns - ssv[l1];
                xpW[w8][90 + l1] = ceq[l1];
            }
            if (l2 < 90) {
                const float r = sigf(giA[l2] + ghA[l2]);
                const float z = sigf(giA[90 + l2] + ghA[90 + l2]);
                const float g = tanhf_(giA[180 + l2] + r * ghA[180 + l2]);
                const float ns = (1.f - z) * g + z * ssv[l2];
                nsvW[w8][l2] = ns;
                xpW[w8][l2] = ns - ssv[l2];
                xpW[w8][90 + l2] = ceq[l2];
            }
        }
        {   // nsync (M=1)
            bf16x8 af[3];
#pragma unroll
            for (int kk = 0; kk < 3; ++kk)
                af[kk] = (lr == 0) ? cvt8(&nsvW[w8][kk * 32 + lh * 8]) : z8;
            const f32x4 d = mm3(af, symF + (size_t)w8 * 1536 + lane * 8);
            if (lh == 0) nsyL[m6] = (m6 < 90) ? d[0] : 0.f;
        }
        {   // pvec (M=1, K=192)
            f32x4 d = f32x4{0.f, 0.f, 0.f, 0.f};
            const unsigned short* bp = wprF + (size_t)w8 * 3072 + lane * 8;
#pragma unroll
            for (int kk = 0; kk < 6; ++kk) {
                const bf16x8 av = (lr == 0) ? cvt8(&xpW[w8][kk * 32 + lh * 8]) : z8;
                d = __builtin_amdgcn_mfma_f32_16x16x32_bf16(av, *(const bf16x8*)(bp + kk * 512), d, 0, 0, 0);
            }
            if (lh == 0) pvL[m6] = (m6 < 90) ? fmaxf(b_prop[m6] + d[0], 0.f) : 0.f;
        }
    } else if (owner) {
        // rfd MFMA on waves 6-7 (independent of nsync)
        const int nnb = nnbS;
        const int pairs = ((nnb + 15) >> 4) * 6;
        for (int p = w8 - 6; p < pairs; p += 2) {
            const int mt = p / 6, nt = p - mt * 6;
            bf16x8 af[3];
            const int jrow = mt * 16 + lr;
            if (jrow < nnb) {
                const float* rp = &hnb[jrow * 96];
#pragma unroll
                for (int kk = 0; kk < 3; ++kk) af[kk] = cvt8(rp + kk * 32 + lh * 8);
            } else { af[0] = z8; af[1] = z8; af[2] = z8; }
            const f32x4 d = mm3(af, syF + (size_t)nt * 1536 + lane * 8);
#pragma unroll
            for (int r4 = 0; r4 < 4; ++r4) {
                const int j = mt * 16 + lh * 4 + r4;
                const int m = nt * 16 + lr;
                if (j < nnb && m < 90)
                    rfd[j * 92 + m] = d[r4] + ws[OFF_CEB + (size_t)nblist[j] * 90 + m];
            }
        }
    }
    __syncthreads();   // ---- barrier 3 ----

    // ================= pass loop: chain (waves 0-1, barrier-free) + gates =================
    const int nact = nactS;
    const int npass0 = (nact + SLOTS - 1) / SLOTS;
    const int npass = (npass0 > 0) ? npass0 : 1;
    for (int pass = 0; pass < npass; ++pass) {
        const int e0p = pass * SLOTS;
        int e1p = e0p + SLOTS; if (e1p > nact) e1p = nact;
        const int na = e1p - e0p;

        if (w8 < 2 && na > 0) {
            for (int st = w8; st * 16 < na; st += 2) {
                const int sb = st * 16;                       // pass-local slot base
                const int nl = (na - sb < 16) ? (na - sb) : 16;

                // --- act: A = hR active rows, B = syF (loop all 6 nt) ---
                bf16x8 afA[3];
                if (lr < nl) {
                    const float* rp = &hR[listS[e0p + sb + lr] * 100];
#pragma unroll
                    for (int kk = 0; kk < 3; ++kk) afA[kk] = cvt8(rp + kk * 32 + lh * 8);
                } else { afA[0] = z8; afA[1] = z8; afA[2] = z8; }
#pragma unroll
                for (int nt = 0; nt < 6; ++nt) {
                    const f32x4 d = mm3(afA, syF + (size_t)nt * 1536 + lane * 8);
                    const int m = nt * 16 + lr;
                    if (m < 90) {
#pragma unroll
                        for (int r4 = 0; r4 < 4; ++r4) {
                            const int tl = lh * 4 + r4;       // tile-local slot
                            if (tl >= nl) continue;
                            const int sl = sb + tl;           // pass-local slot
                            const int r = listS[e0p + sl];
                            const float nv = nbvL[r], sv = svL[r];
                            float s = 0.f;
                            if (nv != 0.f)
                                s = nv * fmaxf(nsyL[m] + ws[OFF_CEB + (size_t)(k0 + r) * 90 + m] + d[r4], 0.f);
                            if (k0 + r == q) {
                                const int nnb = nnbS;
                                const float nm = nsyL[m];
                                for (int j = 0; j < nnb; ++j)
                                    s += nbw[j] * fmaxf(nm + rfd[j * 92 + m], 0.f);
                            }
                            actb[sl * 96 + m] = 0.5f * s + 0.5f * sv * pvL[m];
                        }
                    }
                }

                // --- inf: A = actb rows (same-wave LDS RAW; compiler orders) ---
                bf16x8 afB[3];
                if (lr < nl) {
                    const float* rp = &actb[(sb + lr) * 96];
#pragma unroll
                    for (int kk = 0; kk < 3; ++kk) afB[kk] = cvt8(rp + kk * 32 + lh * 8);
                } else { afB[0] = z8; afB[1] = z8; afB[2] = z8; }
#pragma unroll
                for (int nt = 0; nt < 6; ++nt) {
                    const f32x4 d = mm3(afB, agF + (size_t)nt * 1536 + lane * 8);
                    const int m = nt * 16 + lr;
                    if (m < 90) {
#pragma unroll
                        for (int r4 = 0; r4 < 4; ++r4) {
                            const int tl = lh * 4 + r4;
                            if (tl < nl) infb[(sb + tl) * 96 + m] = fmaxf(baggL[m] + d[r4], 0.f);
                        }
                    }
                }

                // --- gi: A = infb rows, B = wiF (all 17 nt) ---
                bf16x8 afC[3];
                if (lr < nl) {
                    const float* rp = &infb[(sb + lr) * 96];
#pragma unroll
                    for (int kk = 0; kk < 3; ++kk) afC[kk] = cvt8(rp + kk * 32 + lh * 8);
                } else { afC[0] = z8; afC[1] = z8; afC[2] = z8; }
                for (int nt = 0; nt < 17; ++nt) {
                    const f32x4 d = mm3(afC, wiF + (size_t)nt * 1536 + lane * 8);
                    const int c = nt * 16 + lr;
                    if (c < 270) {
#pragma unroll
                        for (int r4 = 0; r4 < 4; ++r4) {
                            const int tl = lh * 4 + r4;
                            if (tl < nl) giL[(sb + tl) * 273 + c] = biL[c] + d[r4];
                        }
                    }
                }
            }
        }
        __syncthreads();   // ---- barrier 4 ----

        // C4: gates (gh acc in registers)
#pragma unroll
        for (int ct = 0; ct < 3; ++ct) {
            const int m = cg * 48 + ct * 16 + lr;
            if (m < 90) {
                const float bhr = bhL[m], bhz = bhL[90 + m], bhg = bhL[180 + m];
#pragma unroll
                for (int r4 = 0; r4 < 4; ++r4) {
                    const int row = rt * 16 + 4 * lh + r4;
                    const int sraw = rowslotS[row];
                    const bool mine = (sraw < 0) ? (pass == 0) : (sraw >= e0p && sraw < e1p);
                    if (!mine) continue;
                    const float* gs = (sraw < 0) ? gi0L : &giL[(sraw - e0p) * 273];
                    const float rg = sigf(gs[m] + acc[0][ct][r4] + bhr);
                    const float zg = sigf(gs[90 + m] + acc[1][ct][r4] + bhz);
                    const float gg = tanhf_(gs[180 + m] + rg * (acc[2][ct][r4] + bhg));
                    const float hold = hR[row * 100 + m];
                    const float hn = (1.f - zg) * gg + zg * hold;
                    hR[row * 100 + m] = hn;
                    stOut[((size_t)(bb * KU + k0 + row)) * 90 + m] = hn;
                }
            }
        }
        __syncthreads();   // ---- barrier 5 ----
    }

    // ================= out head (8 threads/row) =================
    {
        const int row = tid >> 3, j = tid & 7;
        const int m0 = j * 12;
        float p = 0.f;
#pragma unroll
        for (int mm = 0; mm < 12; ++mm) {
            const int m = m0 + mm;
            if (m < 90) p += hR[row * 100 + m] * woutL[m];
        }
#pragma unroll
        for (int o = 1; o < 8; o <<= 1) p += __shfl_xor(p, o);
        if (j == 0)
            out[(size_t)t * NB * KU + (size_t)bb * KU + k0 + row] = sigf(p + b_out[0]);
    }
}

extern "C" void kernel_launch(void* const* d_in, const int* in_sizes, int n_in,
                              void* d_out, int out_size, void* d_ws, size_t ws_size,
                              hipStream_t stream) {
    const int* questions = (const int*)d_in[0];
    const int* answers = (const int*)d_in[1];
    const float* response_emb = (const float*)d_in[2];
    const float* concept_emb = (const float*)d_in[3];
    const float* nb_adj = (const float*)d_in[4];
    const float* succ_adj = (const float*)d_in[5];
    const float* Wi_self = (const float*)d_in[6];
    const float* Wh_self = (const float*)d_in[7];
    const float* bi_self = (const float*)d_in[8];
    const float* bh_self = (const float*)d_in[9];
    const float* Wi_rnn = (const float*)d_in[10];
    const float* Wh_rnn = (const float*)d_in[11];
    const float* bi_rnn = (const float*)d_in[12];
    const float* bh_rnn = (const float*)d_in[13];
    const float* W_sync = (const float*)d_in[14];
    const float* b_sync = (const float*)d_in[15];
    const float* W_prop = (const float*)d_in[16];
    const float* b_prop = (const float*)d_in[17];
    const float* W_agg = (const float*)d_in[18];
    const float* b_agg = (const float*)d_in[19];
    const float* W_out = (const float*)d_in[20];
    const float* b_out = (const float*)d_in[21];

    float* out = (float*)d_out;
    float* stFinal = out + (size_t)NT * NB * KU;   // states region of d_out
    float* ws = (float*)d_ws;

    hipMemsetAsync(stFinal, 0, (size_t)NB * KU * 90 * sizeof(float), stream);
    skt_prep<<<142, 256, 0, stream>>>(concept_emb, W_sync, b_sync, Wi_rnn, Wh_rnn,
                                      Wi_self, Wh_self, W_prop, bi_rnn, b_agg, W_agg, ws);
    for (int t = 0; t < NT; ++t) {
        const float* sin = (t & 1) ? ws : stFinal;
        float* sout = (t & 1) ? stFinal : ws;
        skt_step<<<NB * 8, 512, 0, stream>>>(
            questions, answers, response_emb, concept_emb, nb_adj, succ_adj,
            bi_self, bh_self, bi_rnn, bh_rnn, b_agg, b_prop, W_out, b_out,
            ws, sin, sout, out, t);
    }
}

// Round 15
// 1488.365 us; speedup vs baseline: 5.1443x; 2.3724x over previous
//
#include <hip/hip_runtime.h>

#define KU 512
#define NB 32
#define NT 64
#define TIL 64
#define SLOTS 16
#define NBMAX 40

// ---- ws float offsets ----
#define N_PONG   (KU * NB * 90)
#define OFF_CEB  (N_PONG)                    // ce_sync+b_sync [512][90] f32
#define OFF_GI0  (OFF_CEB + KU * 90)         // gi0 [272] f32
#define OFF_WHTF (OFF_GI0 + 288)             // us[3][6][3][64][8] Wh       (27648 us)
#define OFF_SYF  (OFF_WHTF + 13824)          // us[6][3][64][8]    Wsync_lo (9216 us)
#define OFF_AGF  (OFF_SYF + 4608)            // us[6][3][64][8]    W_agg    (9216 us)
#define OFF_WIF  (OFF_AGF + 4608)            // us[17][3][64][8]   Wi_rnn   (26112 us)
#define OFF_WISF (OFF_WIF + 13056)           // us[17][3][64][8]   Wi_self  (26112 us)
#define OFF_WHSF (OFF_WISF + 13056)          // us[17][3][64][8]   Wh_self  (26112 us)
#define OFF_SYMF (OFF_WHSF + 13056)          // us[6][3][64][8]    Wsync_mid(9216 us)
#define OFF_WPRF (OFF_SYMF + 4608)           // us[6][6][64][8]    W_prop   (18432 us)

typedef short bf16x8 __attribute__((ext_vector_type(8)));
typedef float f32x4 __attribute__((ext_vector_type(4)));

__device__ __forceinline__ float sigf(float x) { return 1.0f / (1.0f + __expf(-x)); }
__device__ __forceinline__ float tanhf_(float x) {
    float e = __expf(2.0f * x);
    return 1.0f - 2.0f / (e + 1.0f);
}
__device__ __forceinline__ unsigned short f2bf(float f) {
    union { float f; unsigned u; } v; v.f = f;
    unsigned r = v.u + 0x7FFFu + ((v.u >> 16) & 1u);
    return (unsigned short)(r >> 16);
}
__device__ __forceinline__ bf16x8 cvt8(const float* p) {
    const float4 a0 = *(const float4*)p;
    const float4 a1 = *(const float4*)(p + 4);
    union { bf16x8 v; unsigned short u[8]; } fr;
    fr.u[0] = f2bf(a0.x); fr.u[1] = f2bf(a0.y); fr.u[2] = f2bf(a0.z); fr.u[3] = f2bf(a0.w);
    fr.u[4] = f2bf(a1.x); fr.u[5] = f2bf(a1.y); fr.u[6] = f2bf(a1.z); fr.u[7] = f2bf(a1.w);
    return fr.v;
}
__device__ __forceinline__ f32x4 mm3(const bf16x8* af, const unsigned short* bp) {
    f32x4 d = f32x4{0.f, 0.f, 0.f, 0.f};
    d = __builtin_amdgcn_mfma_f32_16x16x32_bf16(af[0], *(const bf16x8*)(bp), d, 0, 0, 0);
    d = __builtin_amdgcn_mfma_f32_16x16x32_bf16(af[1], *(const bf16x8*)(bp + 512), d, 0, 0, 0);
    d = __builtin_amdgcn_mfma_f32_16x16x32_bf16(af[2], *(const bf16x8*)(bp + 1024), d, 0, 0, 0);
    return d;
}

// ============ prep: ce_sync + gi0 + all bf16 weight fragments (once) ============
__global__ void skt_prep(const float* __restrict__ concept_emb, const float* __restrict__ W_sync,
                         const float* __restrict__ b_sync, const float* __restrict__ Wi_rnn,
                         const float* __restrict__ Wh_rnn, const float* __restrict__ Wi_self,
                         const float* __restrict__ Wh_self, const float* __restrict__ W_prop,
                         const float* __restrict__ bi_rnn, const float* __restrict__ b_agg,
                         const float* __restrict__ W_agg, float* __restrict__ ws) {
    const int blk = blockIdx.x, tid = threadIdx.x;
    if (blk < 128) {                       // ceb[512][90]
        for (int rr = 0; rr < 4; ++rr) {
            const int k = blk * 4 + rr;
            if (tid < 90) {
                float acc = b_sync[tid];
                for (int kk = 0; kk < 90; ++kk)
                    acc += concept_emb[k * 90 + kk] * W_sync[(180 + kk) * 90 + tid];
                ws[OFF_CEB + k * 90 + tid] = acc;
            }
        }
    } else if (blk < 131) {                // whtF
        const int g = blk - 128;
        unsigned short* p = (unsigned short*)(ws + OFF_WHTF);
        for (int idx = tid; idx < 9216; idx += 256) {
            const int i = idx & 7, lane = (idx >> 3) & 63;
            const int rest = idx >> 9, kk = rest % 3, nb = rest / 3;
            const int n = nb * 16 + (lane & 15);
            const int k = kk * 32 + ((lane >> 4) << 3) + i;
            p[(size_t)g * 9216 + idx] = f2bf((n < 90 && k < 90) ? Wh_rnn[k * 270 + g * 90 + n] : 0.f);
        }
    } else if (blk == 131) {               // gi0
        for (int c = tid; c < 272; c += 256) {
            float acc = 0.f;
            if (c < 270) {
                acc = bi_rnn[c];
                for (int kk = 0; kk < 90; ++kk)
                    acc += fmaxf(b_agg[kk], 0.f) * Wi_rnn[kk * 270 + c];
            }
            ws[OFF_GI0 + c] = acc;
        }
    } else if (blk == 132) {               // syF
        unsigned short* p = (unsigned short*)(ws + OFF_SYF);
        for (int idx = tid; idx < 9216; idx += 256) {
            const int i = idx & 7, lane = (idx >> 3) & 63;
            const int rest = idx >> 9, kk = rest % 3, nt = rest / 3;
            const int n = nt * 16 + (lane & 15);
            const int k = kk * 32 + ((lane >> 4) << 3) + i;
            p[idx] = f2bf((n < 90 && k < 90) ? W_sync[k * 90 + n] : 0.f);
        }
    } else if (blk == 133) {               // agF
        unsigned short* p = (unsigned short*)(ws + OFF_AGF);
        for (int idx = tid; idx < 9216; idx += 256) {
            const int i = idx & 7, lane = (idx >> 3) & 63;
            const int rest = idx >> 9, kk = rest % 3, nt = rest / 3;
            const int n = nt * 16 + (lane & 15);
            const int k = kk * 32 + ((lane >> 4) << 3) + i;
            p[idx] = f2bf((n < 90 && k < 90) ? W_agg[k * 90 + n] : 0.f);
        }
    } else if (blk < 136) {                // wiF
        unsigned short* p = (unsigned short*)(ws + OFF_WIF);
        const int i0 = (blk - 134) * 13056, i1 = i0 + 13056;
        for (int idx = i0 + tid; idx < i1; idx += 256) {
            const int i = idx & 7, lane = (idx >> 3) & 63;
            const int rest = idx >> 9, kk = rest % 3, nt = rest / 3;
            const int n = nt * 16 + (lane & 15);
            const int k = kk * 32 + ((lane >> 4) << 3) + i;
            p[idx] = f2bf((n < 270 && k < 90) ? Wi_rnn[k * 270 + n] : 0.f);
        }
    } else if (blk < 138) {                // wisF
        unsigned short* p = (unsigned short*)(ws + OFF_WISF);
        const int i0 = (blk - 136) * 13056, i1 = i0 + 13056;
        for (int idx = i0 + tid; idx < i1; idx += 256) {
            const int i = idx & 7, lane = (idx >> 3) & 63;
            const int rest = idx >> 9, kk = rest % 3, nt = rest / 3;
            const int n = nt * 16 + (lane & 15);
            const int k = kk * 32 + ((lane >> 4) << 3) + i;
            p[idx] = f2bf((n < 270 && k < 90) ? Wi_self[k * 270 + n] : 0.f);
        }
    } else if (blk < 140) {                // whsF
        unsigned short* p = (unsigned short*)(ws + OFF_WHSF);
        const int i0 = (blk - 138) * 13056, i1 = i0 + 13056;
        for (int idx = i0 + tid; idx < i1; idx += 256) {
            const int i = idx & 7, lane = (idx >> 3) & 63;
            const int rest = idx >> 9, kk = rest % 3, nt = rest / 3;
            const int n = nt * 16 + (lane & 15);
            const int k = kk * 32 + ((lane >> 4) << 3) + i;
            p[idx] = f2bf((n < 270 && k < 90) ? Wh_self[k * 270 + n] : 0.f);
        }
    } else if (blk == 140) {               // symF
        unsigned short* p = (unsigned short*)(ws + OFF_SYMF);
        for (int idx = tid; idx < 9216; idx += 256) {
            const int i = idx & 7, lane = (idx >> 3) & 63;
            const int rest = idx >> 9, kk = rest % 3, nt = rest / 3;
            const int n = nt * 16 + (lane & 15);
            const int k = kk * 32 + ((lane >> 4) << 3) + i;
            p[idx] = f2bf((n < 90 && k < 90) ? W_sync[(90 + k) * 90 + n] : 0.f);
        }
    } else {                               // wprF (K=192 padded)
        unsigned short* p = (unsigned short*)(ws + OFF_WPRF);
        for (int idx = tid; idx < 18432; idx += 256) {
            const int i = idx & 7, lane = (idx >> 3) & 63;
            const int rest = idx >> 9, kk = rest % 6, nt = rest / 6;
            const int n = nt * 16 + (lane & 15);
            const int k = kk * 32 + ((lane >> 4) << 3) + i;
            p[idx] = f2bf((n < 90 && k < 180) ? W_prop[k * 90 + n] : 0.f);
        }
    }
}

// ============ per-step kernel: 256 blocks x 512 thr, TIL=64, 6 barriers/step ============
__global__ __launch_bounds__(512, 1) void skt_step(
    const int* __restrict__ qs, const int* __restrict__ as_,
    const float* __restrict__ response_emb, const float* __restrict__ concept_emb,
    const float* __restrict__ nb_adj, const float* __restrict__ succ_adj,
    const float* __restrict__ bi_self, const float* __restrict__ bh_self,
    const float* __restrict__ bi_rnn, const float* __restrict__ bh_rnn,
    const float* __restrict__ b_agg, const float* __restrict__ b_prop,
    const float* __restrict__ W_out, const float* __restrict__ b_out,
    float* __restrict__ ws, const float* __restrict__ stIn, float* __restrict__ stOut,
    float* __restrict__ out, int t) {
    __shared__ alignas(16) float hR[TIL * 100];
    __shared__ alignas(16) float hnb[NBMAX * 96];
    __shared__ alignas(16) float rfd[NBMAX * 92];
    __shared__ alignas(16) float giL[SLOTS * 273];
    __shared__ alignas(16) float actb[SLOTS * 96], infb[SLOTS * 96];
    __shared__ alignas(16) float giA[272], ghA[272];
    __shared__ alignas(16) float gi0L[273], biL[273], bhL[272];
    __shared__ alignas(16) float re[96], ssv[96], ceq[96];
    __shared__ alignas(16) float nsvW[6][96], xpW[6][192];
    __shared__ alignas(16) float nsyL[96], pvL[96], baggL[96];
    __shared__ float nbw[NBMAX];
    __shared__ int nblist[NBMAX];
    __shared__ float nbvL[TIL], svL[TIL];
    __shared__ int rowslotS[TIL], listS[TIL];
    __shared__ int nactS, nnbS;

    const int tid = threadIdx.x;
    const int bb = blockIdx.x >> 3;
    const int k0 = (blockIdx.x & 7) * TIL;
    const int q = qs[bb * NT + t];
    const int a = as_[bb * NT + t];
    const bool owner = (q >= k0 && q < k0 + TIL);

    const int w8 = tid >> 6, lane = tid & 63;
    const int lr = lane & 15, lh = lane >> 4;
    const int rt = w8 & 3, cg = w8 >> 2;
    const bf16x8 z8 = {0, 0, 0, 0, 0, 0, 0, 0};

    const unsigned short* whtF = (const unsigned short*)(ws + OFF_WHTF);
    const unsigned short* syF = (const unsigned short*)(ws + OFF_SYF);
    const unsigned short* agF = (const unsigned short*)(ws + OFF_AGF);
    const unsigned short* wiF = (const unsigned short*)(ws + OFF_WIF);
    const unsigned short* wisF = (const unsigned short*)(ws + OFF_WISF);
    const unsigned short* whsF = (const unsigned short*)(ws + OFF_WHSF);
    const unsigned short* symF = (const unsigned short*)(ws + OFF_SYMF);
    const unsigned short* wprF = (const unsigned short*)(ws + OFF_WPRF);

    // ================= B0: stage + scans + out(t-1) =================
    if (tid < 384) {                     // hR 64 x 50 float2 (cols 90..99 zero)
        for (int idx = tid; idx < TIL * 50; idx += 384) {
            const int row = idx / 50, c2 = idx - row * 50;
            float2 v = make_float2(0.f, 0.f);
            if (c2 < 45)
                v = ((const float2*)(stIn + ((size_t)(bb * KU + k0 + row)) * 90))[c2];
            *(float2*)&hR[row * 100 + 2 * c2] = v;
        }
    } else if (tid < 448) {              // wave 6: active-row scan
        const int l = tid - 384;
        const int kg = k0 + l;
        const float nv = nb_adj[(size_t)q * KU + kg];
        const float sv = succ_adj[(size_t)q * KU + kg];
        nbvL[l] = nv; svL[l] = sv;
        const bool act = (nv != 0.f) || (sv != 0.f) || (kg == q);
        const unsigned long long mb = __ballot(act);
        const int rank = (int)__popcll(mb & ((1ull << l) - 1ull));
        rowslotS[l] = act ? rank : -1;
        if (act) listS[rank] = l;
        if (l == 0) nactS = (int)__popcll(mb);
    } else {                             // wave 7: neighbor scan of q
        const int l = tid - 448;
        int base = 0;
        for (int ch = 0; ch < 8; ++ch) {
            const int kp = ch * 64 + l;
            const float nv = nb_adj[(size_t)q * KU + kp];
            const unsigned long long mb = __ballot(nv != 0.f);
            const int idx = base + (int)__popcll(mb & ((1ull << l) - 1ull));
            if (nv != 0.f && idx < NBMAX) { nblist[idx] = kp; nbw[idx] = nv; }
            base += (int)__popcll(mb);
        }
        if (l == 0) nnbS = (base < NBMAX) ? base : NBMAX;
    }
    for (int j = tid; j < 270; j += 512) {
        if (j < 90) re[j] = response_emb[(size_t)a * 90 + j];
        else if (j < 180) ssv[j - 90] = stIn[((size_t)(bb * KU + q)) * 90 + (j - 90)];
        else ceq[j - 180] = concept_emb[(size_t)q * 90 + (j - 180)];
    }
    for (int c = tid; c < 273; c += 512) {
        gi0L[c] = (c < 272) ? ws[OFF_GI0 + c] : 0.f;
        biL[c] = (c < 270) ? bi_rnn[c] : 0.f;
        if (c < 272) bhL[c] = (c < 270) ? bh_rnn[c] : 0.f;
    }
    if (tid < 96) {
        baggL[tid] = (tid < 90) ? b_agg[tid] : 0.f;
        if (tid >= 90) { re[tid] = 0.f; ssv[tid] = 0.f; ceq[tid] = 0.f; }
    } else if (tid < 132) {
        nsvW[(tid - 96) / 6][90 + (tid - 96) % 6] = 0.f;
    } else if (tid < 204) {
        xpW[(tid - 132) / 12][180 + (tid - 132) % 12] = 0.f;
    }
    for (int j2 = tid; j2 < SLOTS * 6 * 2; j2 += 512) {
        const int half = j2 >= SLOTS * 6;
        const int jj = half ? j2 - SLOTS * 6 : j2;
        (half ? infb : actb)[(jj / 6) * 96 + 90 + (jj % 6)] = 0.f;
    }
    // out(t-1) from stIn (free: overlapped with staging)
    if (t > 0) {
        const int row = tid >> 3, j = tid & 7;
        const float* sp = stIn + ((size_t)(bb * KU + k0 + row)) * 90;
        float p = 0.f;
#pragma unroll
        for (int mm = 0; mm < 12; ++mm) {
            const int m = j * 12 + mm;
            if (m < 90) p += sp[m] * W_out[m];
        }
#pragma unroll
        for (int o = 1; o < 8; o <<= 1) p += __shfl_xor(p, o);
        if (j == 0)
            out[(size_t)(t - 1) * NB * KU + (size_t)bb * KU + k0 + row] = sigf(p + b_out[0]);
    }
    __syncthreads();   // ---- barrier 1 ----

    // ================= B1: owner hnb gather | self-GRU MFMA | gh GEMM =================
    if (owner) {
        const int nnb = nnbS;
        for (int i = tid; i < nnb * 48; i += 512) {
            const int j = i / 48, c2 = i - j * 48;
            float2 v = make_float2(0.f, 0.f);
            if (c2 < 45)
                v = ((const float2*)(stIn + ((size_t)(bb * KU + nblist[j])) * 90))[c2];
            *(float2*)&hnb[j * 96 + 2 * c2] = v;
        }
    }
    {   // self-GRU matvecs via M=2 MFMA: A row0=re, row1=ssv
        bf16x8 af[3];
#pragma unroll
        for (int kk = 0; kk < 3; ++kk)
            af[kk] = (lr == 0) ? cvt8(&re[kk * 32 + lh * 8])
                   : ((lr == 1) ? cvt8(&ssv[kk * 32 + lh * 8]) : z8);
        for (int nt = w8; nt < 17; nt += 8) {
            const f32x4 dwi = mm3(af, wisF + (size_t)nt * 1536 + lane * 8);
            const f32x4 dwh = mm3(af, whsF + (size_t)nt * 1536 + lane * 8);
            if (lh == 0) {
                const int c = nt * 16 + lr;
                if (c < 270) { giA[c] = bi_self[c] + dwi[0]; ghA[c] = bh_self[c] + dwh[1]; }
            }
        }
    }
    // gh GEMM: A = own hR rows, B = whtF
    f32x4 acc[3][3];
#pragma unroll
    for (int g = 0; g < 3; ++g)
#pragma unroll
        for (int ct = 0; ct < 3; ++ct) acc[g][ct] = f32x4{0.f, 0.f, 0.f, 0.f};
    {
        bf16x8 afr[3];
        const float* ar = &hR[(rt * 16 + lr) * 100];
#pragma unroll
        for (int kk = 0; kk < 3; ++kk) afr[kk] = cvt8(ar + kk * 32 + lh * 8);
#pragma unroll
        for (int g = 0; g < 3; ++g) {
#pragma unroll
            for (int ct = 0; ct < 3; ++ct) {
                const int nb = cg * 3 + ct;
                const unsigned short* bp = whtF + (size_t)(g * 6 + nb) * 1536 + lane * 8;
                acc[g][ct] = __builtin_amdgcn_mfma_f32_16x16x32_bf16(afr[0], *(const bf16x8*)(bp), acc[g][ct], 0, 0, 0);
                acc[g][ct] = __builtin_amdgcn_mfma_f32_16x16x32_bf16(afr[1], *(const bf16x8*)(bp + 512), acc[g][ct], 0, 0, 0);
                acc[g][ct] = __builtin_amdgcn_mfma_f32_16x16x32_bf16(afr[2], *(const bf16x8*)(bp + 1024), acc[g][ct], 0, 0, 0);
            }
        }
    }
    __syncthreads();   // ---- barrier 2 ----

    // ================= B2': nsv/xprop per-wave + nsync/pvec (w<6) | rfd (w6-7, owner) ====
    const int m6 = w8 * 16 + lr;
    if (w8 < 6) {
        {   // wave-local nsv / xprop (redundant per wave; identical f32 math)
            const int l1 = lane, l2 = lane + 64;
            if (l1 < 90) {
                const float r = sigf(giA[l1] + ghA[l1]);
                const float z = sigf(giA[90 + l1] + ghA[90 + l1]);
                const float g = tanhf_(giA[180 + l1] + r * ghA[180 + l1]);
                const float ns = (1.f - z) * g + z * ssv[l1];
                nsvW[w8][l1] = ns;
                xpW[w8][l1] = ns - ssv[l1];
                xpW[w8][90 + l1] = ceq[l1];
            }
            if (l2 < 90) {
                const float r = sigf(giA[l2] + ghA[l2]);
                const float z = sigf(giA[90 + l2] + ghA[90 + l2]);
                const float g = tanhf_(giA[180 + l2] + r * ghA[180 + l2]);
                const float ns = (1.f - z) * g + z * ssv[l2];
                nsvW[w8][l2] = ns;
                xpW[w8][l2] = ns - ssv[l2];
                xpW[w8][90 + l2] = ceq[l2];
            }
        }
        {   // nsync (M=1)
            bf16x8 af[3];
#pragma unroll
            for (int kk = 0; kk < 3; ++kk)
                af[kk] = (lr == 0) ? cvt8(&nsvW[w8][kk * 32 + lh * 8]) : z8;
            const f32x4 d = mm3(af, symF + (size_t)w8 * 1536 + lane * 8);
            if (lh == 0) nsyL[m6] = (m6 < 90) ? d[0] : 0.f;
        }
        {   // pvec (M=1, K=192)
            f32x4 d = f32x4{0.f, 0.f, 0.f, 0.f};
            const unsigned short* bp = wprF + (size_t)w8 * 3072 + lane * 8;
#pragma unroll
            for (int kk = 0; kk < 6; ++kk) {
                const bf16x8 av = (lr == 0) ? cvt8(&xpW[w8][kk * 32 + lh * 8]) : z8;
                d = __builtin_amdgcn_mfma_f32_16x16x32_bf16(av, *(const bf16x8*)(bp + kk * 512), d, 0, 0, 0);
            }
            if (lh == 0) pvL[m6] = (m6 < 90) ? fmaxf(b_prop[m6] + d[0], 0.f) : 0.f;
        }
    } else if (owner) {
        // rfd MFMA on waves 6-7 (independent of nsync)
        const int nnb = nnbS;
        const int pairs = ((nnb + 15) >> 4) * 6;
        for (int p = w8 - 6; p < pairs; p += 2) {
            const int mt = p / 6, nt = p - mt * 6;
            bf16x8 af[3];
            const int jrow = mt * 16 + lr;
            if (jrow < nnb) {
                const float* rp = &hnb[jrow * 96];
#pragma unroll
                for (int kk = 0; kk < 3; ++kk) af[kk] = cvt8(rp + kk * 32 + lh * 8);
            } else { af[0] = z8; af[1] = z8; af[2] = z8; }
            const f32x4 d = mm3(af, syF + (size_t)nt * 1536 + lane * 8);
#pragma unroll
            for (int r4 = 0; r4 < 4; ++r4) {
                const int j = mt * 16 + lh * 4 + r4;
                const int m = nt * 16 + lr;
                if (j < nnb && m < 90)
                    rfd[j * 92 + m] = d[r4] + ws[OFF_CEB + (size_t)nblist[j] * 90 + m];
            }
        }
    }
    __syncthreads();   // ---- barrier 3 ----

    // ================= C: MFMA chains + gates (multi-pass; champion structure) ==========
    const int nact = nactS;
    const int npass0 = (nact + SLOTS - 1) / SLOTS;
    const int npass = (npass0 > 0) ? npass0 : 1;
    for (int pass = 0; pass < npass; ++pass) {
        const int e0p = pass * SLOTS;
        int e1p = e0p + SLOTS; if (e1p > nact) e1p = nact;
        const int na = e1p - e0p;

        // C1: act
        if (na > 0 && w8 < 6) {
            const int nt = w8;
            bf16x8 af[3];
            if (lr < na) {
                const float* rp = &hR[listS[e0p + lr] * 100];
#pragma unroll
                for (int kk = 0; kk < 3; ++kk) af[kk] = cvt8(rp + kk * 32 + lh * 8);
            } else { af[0] = z8; af[1] = z8; af[2] = z8; }
            const f32x4 d = mm3(af, syF + (size_t)nt * 1536 + lane * 8);
            const int m = nt * 16 + lr;
            if (m < 90) {
#pragma unroll
                for (int r4 = 0; r4 < 4; ++r4) {
                    const int slot = lh * 4 + r4;
                    if (slot >= na) continue;
                    const int r = listS[e0p + slot];
                    const float nv = nbvL[r], sv = svL[r];
                    float s = 0.f;
                    if (nv != 0.f)
                        s = nv * fmaxf(nsyL[m] + ws[OFF_CEB + (size_t)(k0 + r) * 90 + m] + d[r4], 0.f);
                    if (k0 + r == q) {
                        const int nnb = nnbS;
                        const float nm = nsyL[m];
                        for (int j = 0; j < nnb; ++j)
                            s += nbw[j] * fmaxf(nm + rfd[j * 92 + m], 0.f);
                    }
                    actb[slot * 96 + m] = 0.5f * s + 0.5f * sv * pvL[m];
                }
            }
        }
        __syncthreads();   // ---- barrier 4 ----

        // C2: inf
        if (na > 0 && w8 < 6) {
            const int nt = w8;
            bf16x8 af[3];
            if (lr < na) {
                const float* rp = &actb[lr * 96];
#pragma unroll
                for (int kk = 0; kk < 3; ++kk) af[kk] = cvt8(rp + kk * 32 + lh * 8);
            } else { af[0] = z8; af[1] = z8; af[2] = z8; }
            const f32x4 d = mm3(af, agF + (size_t)nt * 1536 + lane * 8);
            const int m = nt * 16 + lr;
            if (m < 90) {
#pragma unroll
                for (int r4 = 0; r4 < 4; ++r4) {
                    const int slot = lh * 4 + r4;
                    if (slot < na) infb[slot * 96 + m] = fmaxf(baggL[m] + d[r4], 0.f);
                }
            }
        }
        __syncthreads();   // ---- barrier 5 ----

        // C3: gi
        if (na > 0) {
            bf16x8 af[3];
            if (lr < na) {
                const float* rp = &infb[lr * 96];
#pragma unroll
                for (int kk = 0; kk < 3; ++kk) af[kk] = cvt8(rp + kk * 32 + lh * 8);
            } else { af[0] = z8; af[1] = z8; af[2] = z8; }
            for (int nt = w8; nt < 17; nt += 8) {
                const f32x4 d = mm3(af, wiF + (size_t)nt * 1536 + lane * 8);
                const int c = nt * 16 + lr;
                if (c < 270) {
#pragma unroll
                    for (int r4 = 0; r4 < 4; ++r4) {
                        const int slot = lh * 4 + r4;
                        if (slot < na) giL[slot * 273 + c] = biL[c] + d[r4];
                    }
                }
            }
        }
        __syncthreads();   // ---- barrier 6 ----

        // C4: gates (gh acc in registers); last pass ends the kernel (no barrier)
#pragma unroll
        for (int ct = 0; ct < 3; ++ct) {
            const int m = cg * 48 + ct * 16 + lr;
            if (m < 90) {
                const float bhr = bhL[m], bhz = bhL[90 + m], bhg = bhL[180 + m];
#pragma unroll
                for (int r4 = 0; r4 < 4; ++r4) {
                    const int row = rt * 16 + 4 * lh + r4;
                    const int sraw = rowslotS[row];
                    const bool mine = (sraw < 0) ? (pass == 0) : (sraw >= e0p && sraw < e1p);
                    if (!mine) continue;
                    const float* gs = (sraw < 0) ? gi0L : &giL[(sraw - e0p) * 273];
                    const float rg = sigf(gs[m] + acc[0][ct][r4] + bhr);
                    const float zg = sigf(gs[90 + m] + acc[1][ct][r4] + bhz);
                    const float gg = tanhf_(gs[180 + m] + rg * (acc[2][ct][r4] + bhg));
                    const float hold = hR[row * 100 + m];
                    const float hn = (1.f - zg) * gg + zg * hold;
                    hR[row * 100 + m] = hn;
                    stOut[((size_t)(bb * KU + k0 + row)) * 90 + m] = hn;
                }
            }
        }
        if (pass + 1 < npass) __syncthreads();
    }
}

// ============ finalize: out[NT-1] from final states ============
__global__ __launch_bounds__(512, 1) void skt_final(
    const float* __restrict__ stFinal, const float* __restrict__ W_out,
    const float* __restrict__ b_out, float* __restrict__ out) {
    const int tid = threadIdx.x;
    const int bb = blockIdx.x >> 3;
    const int k0 = (blockIdx.x & 7) * TIL;
    const int row = tid >> 3, j = tid & 7;
    const float* sp = stFinal + ((size_t)(bb * KU + k0 + row)) * 90;
    float p = 0.f;
#pragma unroll
    for (int mm = 0; mm < 12; ++mm) {
        const int m = j * 12 + mm;
        if (m < 90) p += sp[m] * W_out[m];
    }
#pragma unroll
    for (int o = 1; o < 8; o <<= 1) p += __shfl_xor(p, o);
    if (j == 0)
        out[(size_t)(NT - 1) * NB * KU + (size_t)bb * KU + k0 + row] = sigf(p + b_out[0]);
}

extern "C" void kernel_launch(void* const* d_in, const int* in_sizes, int n_in,
                              void* d_out, int out_size, void* d_ws, size_t ws_size,
                              hipStream_t stream) {
    const int* questions = (const int*)d_in[0];
    const int* answers = (const int*)d_in[1];
    const float* response_emb = (const float*)d_in[2];
    const float* concept_emb = (const float*)d_in[3];
    const float* nb_adj = (const float*)d_in[4];
    const float* succ_adj = (const float*)d_in[5];
    const float* Wi_self = (const float*)d_in[6];
    const float* Wh_self = (const float*)d_in[7];
    const float* bi_self = (const float*)d_in[8];
    const float* bh_self = (const float*)d_in[9];
    const float* Wi_rnn = (const float*)d_in[10];
    const float* Wh_rnn = (const float*)d_in[11];
    const float* bi_rnn = (const float*)d_in[12];
    const float* bh_rnn = (const float*)d_in[13];
    const float* W_sync = (const float*)d_in[14];
    const float* b_sync = (const float*)d_in[15];
    const float* W_prop = (const float*)d_in[16];
    const float* b_prop = (const float*)d_in[17];
    const float* W_agg = (const float*)d_in[18];
    const float* b_agg = (const float*)d_in[19];
    const float* W_out = (const float*)d_in[20];
    const float* b_out = (const float*)d_in[21];

    float* out = (float*)d_out;
    float* stFinal = out + (size_t)NT * NB * KU;   // states region of d_out
    float* ws = (float*)d_ws;

    hipMemsetAsync(stFinal, 0, (size_t)NB * KU * 90 * sizeof(float), stream);
    skt_prep<<<142, 256, 0, stream>>>(concept_emb, W_sync, b_sync, Wi_rnn, Wh_rnn,
                                      Wi_self, Wh_self, W_prop, bi_rnn, b_agg, W_agg, ws);
    for (int t = 0; t < NT; ++t) {
        const float* sin = (t & 1) ? ws : stFinal;
        float* sout = (t & 1) ? stFinal : ws;
        skt_step<<<NB * 8, 512, 0, stream>>>(
            questions, answers, response_emb, concept_emb, nb_adj, succ_adj,
            bi_self, bh_self, bi_rnn, bh_rnn, b_agg, b_prop, W_out, b_out,
            ws, sin, sout, out, t);
    }
    skt_final<<<NB * 8, 512, 0, stream>>>(stFinal, W_out, b_out, out);
}